// Round 10
// baseline (805.164 us; speedup 1.0000x reference)
//
#include <hip/hip_runtime.h>
#include <hip/hip_bf16.h>
#include <cstdint>

// Problem dims
#define BB 16
#define CC 64
#define NN 512
#define TT 64
#define KCH 3
#define PP (BB*NN*TT)      // 524288 points
#define EPSB 1e-5f

typedef __bf16 bf16;
typedef __bf16 bf16x8 __attribute__((ext_vector_type(8)));
typedef __bf16 bf16x4 __attribute__((ext_vector_type(4)));
typedef float  f32x4  __attribute__((ext_vector_type(4)));
typedef float  f32x16 __attribute__((ext_vector_type(16)));

#define MFMA16(A,Bv,Cv) __builtin_amdgcn_mfma_f32_16x16x32_bf16((A),(Bv),(Cv),0,0,0)
#define MFMA32(A,Bv,Cv) __builtin_amdgcn_mfma_f32_32x32x16_bf16((A),(Bv),(Cv),0,0,0)

// ---------------- prep (merged): adjb transpose + weight fragment prep -----
__global__ __launch_bounds__(256) void k_prep(const float* __restrict__ adj,
    const float* __restrict__ w1, const float* __restrict__ w2,
    const float* __restrict__ cw, const float* __restrict__ gw,
    const float* __restrict__ rw, bf16* __restrict__ adjb,
    bf16* __restrict__ w1p, bf16* __restrict__ w2p, bf16* __restrict__ cp,
    bf16* __restrict__ gp, bf16* __restrict__ rp){
  int blk = blockIdx.x, tid = threadIdx.x;
  if (blk < 3072){
    int idx = blk*256 + tid;
    int m = idx & 511, n = (idx >> 9) & 511, k = idx >> 18;
    adjb[idx] = (bf16)adj[((size_t)(k*512 + m))*512 + n];
    return;
  }
  int e0 = (blk - 3072)*256 + tid;                  // [0, 24576)
  if (e0 < 12288){                                  // K=192 groups (conv & cheb)
    int e = e0;
    int j = e&7, lane = (e>>3)&63, cf = (e>>9)&3, ks = e>>11;
    int k = ks*32 + (lane>>4)*8 + j, col = cf*16 + (lane&15);
    int kk = k >> 6, i = k & 63;
    w1p[e] = (bf16)w1[(col*64 + i)*3 + kk];
    w2p[e] = (bf16)w2[(col*64 + i)*3 + kk];
    cp[e]  = (bf16)cw[((size_t)kk*64 + i)*64 + col];
  } else if (e0 < 20480){                           // K=128 (gate)
    int e = e0 - 12288;
    int j = e&7, lane = (e>>3)&63, cf = (e>>9)&3, ks = e>>11;
    int k = ks*32 + (lane>>4)*8 + j, col = cf*16 + (lane&15);
    gp[e] = (bf16)gw[col*128 + k];
  } else {                                          // K=64 (res)
    int e = e0 - 20480;
    int j = e&7, lane = (e>>3)&63, cf = (e>>9)&3, ks = e>>11;
    int k = ks*32 + (lane>>4)*8 + j, col = cf*16 + (lane&15);
    rp[e] = (bf16)rw[col*64 + k];
  }
}

// ---------------- fused x prep: one read of x -> xlb AND xmt ----------------
__global__ __launch_bounds__(256) void k_xprep(const float* __restrict__ x,
    bf16* __restrict__ xlb, bf16* __restrict__ xmt){
  __shared__ bf16 T[32768];               // 64KB
  int bid = blockIdx.x;
  int b = bid >> 6, i0 = ((bid >> 3) & 7)*8, n0 = (bid & 7)*64;
  int tid = threadIdx.x;
  #pragma unroll 4
  for (int it = 0; it < 32; ++it){
    int flat = it*256 + tid;              // [0,8192)
    int t4 = flat & 15, n = (flat >> 4) & 63, i = flat >> 10;
    float4 v = *reinterpret_cast<const float4*>(
        x + ((size_t)((b*64 + i0 + i)*512) + (n0 + n))*64 + t4*4);
    int s = t4 ^ ((n + 2*i) & 15);
    bf16x4 pk; pk[0]=(bf16)v.x; pk[1]=(bf16)v.y; pk[2]=(bf16)v.z; pk[3]=(bf16)v.w;
    *reinterpret_cast<bf16x4*>(&T[(i*64 + n)*64 + s*4]) = pk;
  }
  __syncthreads();
  // xmt emission
  #pragma unroll 4
  for (int it = 0; it < 16; ++it){
    int flat = it*256 + tid;              // [0,4096)
    int mc = flat & 7, i = (flat >> 3) & 7, t = flat >> 6;
    bf16x8 o;
    #pragma unroll
    for (int e = 0; e < 8; ++e){
      int m = mc*8 + e;
      int s = (t >> 2) ^ ((m + 2*i) & 15);
      o[e] = T[(i*64 + m)*64 + s*4 + (t & 3)];
    }
    *reinterpret_cast<bf16x8*>(
        &xmt[((size_t)((b*64 + t)*64) + i0 + i)*512 + n0 + mc*8]) = o;
  }
  // xlb emission
  #pragma unroll 4
  for (int it = 0; it < 16; ++it){
    int flat = it*256 + tid;              // [0,4096)
    int t = flat & 63, n = flat >> 6;
    bf16x8 o;
    #pragma unroll
    for (int e = 0; e < 8; ++e){
      int s = (t >> 2) ^ ((n + 2*e) & 15);
      o[e] = T[(e*64 + n)*64 + s*4 + (t & 3)];
    }
    *reinterpret_cast<bf16x8*>(
        &xlb[(((size_t)b*512 + n0 + n)*64 + t)*64 + i0]) = o;
  }
}

// ---------------- temporal conv (1x3) as tall GEMM; optional BN+relu on load
__global__ __launch_bounds__(256,4) void k_conv(const bf16* __restrict__ in,
    const bf16* __restrict__ wp, bf16* __restrict__ outp, float* __restrict__ part,
    const float* __restrict__ sc, const float* __restrict__ sh){
  int tid = threadIdx.x, w = tid >> 6, l = tid & 63, l15 = l & 15, lg = l >> 4;
  int blk = blockIdx.x;
  size_t rowbase = (size_t)blk * 64;
  const bf16* xr = in + rowbase * 64;
  int t = w*16 + l15;
  f32x4 acc[4] = {};
  #pragma unroll
  for (int ks = 0; ks < 6; ++ks){
    int dt = ks >> 1, kh = ks & 1;
    int ts = t + dt - 1;
    bf16x8 a = {};
    if (ts >= 0 && ts < 64){
      a = *reinterpret_cast<const bf16x8*>(xr + ts*64 + kh*32 + lg*8);
      if (sc){                                  // BN1+relu applied on load
        int i0 = kh*32 + lg*8;
        #pragma unroll
        for (int e = 0; e < 8; ++e){
          float f = (float)a[e]*sc[i0+e] + sh[i0+e];
          a[e] = (bf16)fmaxf(f, 0.f);
        }
      }
    }
    #pragma unroll
    for (int cf = 0; cf < 4; ++cf){
      bf16x8 bfr = *reinterpret_cast<const bf16x8*>(wp + ((ks*4 + cf)*64 + l)*8);
      acc[cf] = MFMA16(a, bfr, acc[cf]);
    }
  }
  __shared__ float ssum[4][4][16], ssq[4][4][16];
  #pragma unroll
  for (int cf = 0; cf < 4; ++cf){
    int o = cf*16 + l15;
    float s = 0.f, q = 0.f;
    #pragma unroll
    for (int r = 0; r < 4; ++r){
      float vv = acc[cf][r];
      int to = w*16 + lg*4 + r;
      outp[(rowbase + to)*64 + o] = (bf16)vv;
      s += vv; q += vv*vv;
    }
    s += __shfl_xor(s, 16); s += __shfl_xor(s, 32);
    q += __shfl_xor(q, 16); q += __shfl_xor(q, 32);
    if (lg == 0){ ssum[w][cf][l15] = s; ssq[w][cf][l15] = q; }
  }
  __syncthreads();
  if (tid < 64){
    int cf = tid >> 4, c = tid & 15;
    float s = ssum[0][cf][c]+ssum[1][cf][c]+ssum[2][cf][c]+ssum[3][cf][c];
    float q = ssq[0][cf][c]+ssq[1][cf][c]+ssq[2][cf][c]+ssq[3][cf][c];
    part[(size_t)blk*128 + tid*2]     = s;
    part[(size_t)blk*128 + tid*2 + 1] = q;
  }
}

// ---------------- BN stats finalize: partials -> scale/shift ----------------
__global__ __launch_bounds__(256) void k_stats(const float* __restrict__ part, int nb,
    const float* __restrict__ g, const float* __restrict__ be,
    float* __restrict__ sc, float* __restrict__ sh){
  int c = blockIdx.x, tid = threadIdx.x;
  float s = 0.f, q = 0.f;
  for (int i = tid; i < nb; i += 256){
    s += part[(size_t)i*128 + c*2];
    q += part[(size_t)i*128 + c*2 + 1];
  }
  __shared__ float rs[256], rq[256];
  rs[tid] = s; rq[tid] = q; __syncthreads();
  for (int st = 128; st > 0; st >>= 1){
    if (tid < st){ rs[tid] += rs[tid+st]; rq[tid] += rq[tid+st]; }
    __syncthreads();
  }
  if (tid == 0){
    float cnt = (float)PP;
    float mean = rs[0]/cnt, var = rq[0]/cnt - mean*mean;
    float r = rsqrtf(var + EPSB);
    sc[c] = g[c]*r;
    sh[c] = be[c] - mean*g[c]*r;
  }
}

// ---------------- fused GEMM1+cheb: spm[(b,n,t)][o] ------------------------
// v9: register-direct AITER-style main loop. NO LDS staging, NO barriers in
// the K-loop: per-lane global loads feed 32x32x16 MFMA fragments directly
// (A row j=l&31 from xmt, B row n=l&31 from adjb; k-permutation within K=16
// cancels between A and B). BK=64 batches consume full 128B lines. Register
// double-buffer (cur/nxt), fully unrolled. Per-wave 32(j) x 64(n) tile.
// VT dump (32x32 C-layout) + cheb contraction + epilogue kept from R9.
__global__ __launch_bounds__(512,2) void k_gemm1(const bf16* __restrict__ xmt,
    const bf16* __restrict__ adjb, const bf16* __restrict__ cp,
    const float* __restrict__ cb, bf16* __restrict__ spm){
  __shared__ bf16 VT[128*128];          // 32KB; VT[n][j] swz; reused SP[256][64]

  int tid = threadIdx.x, w = tid >> 6, l = tid & 63, l15 = l & 15, lg = l >> 4;
  int l31 = l & 31, lh = l >> 5;
  int wjt = w >> 1, wn = w & 1;         // j 32-tile (0..3), n 64-half (0..1)

  // bijective XCD swizzle over 2048 blocks; nt innermost (A-panel shared by 4)
  int orig = blockIdx.x;
  int wg = (orig & 7) * 256 + (orig >> 3);
  int jt = wg >> 2, nt = wg & 3;
  int J0 = jt*128, N0 = nt*128;

  // per-lane fragment row pointers (element units); +lh*8 selects k-half
  const bf16* arow = xmt + (size_t)(J0 + wjt*32 + l31)*512 + lh*8;
  const bf16* brow0 = adjb + (size_t)(N0 + wn*64 + l31)*512 + lh*8;
  const bf16* brow1 = brow0 + (size_t)32*512;

  f32x16 acc0, acc1;
  f32x4 acc2[2][4] = {};

  for (int kk = 0; kk < 3; ++kk){
    size_t ko = (size_t)kk*512*512;
    #pragma unroll
    for (int e = 0; e < 16; ++e){ acc0[e] = 0.f; acc1[e] = 0.f; }

    // register double-buffered K-loop: 8 steps of BK=64 (4 ksub of K=16)
    bf16x8 aC[4], b0C[4], b1C[4], aN[4], b0N[4], b1N[4];
    #pragma unroll
    for (int s = 0; s < 4; ++s){
      aC[s]  = *reinterpret_cast<const bf16x8*>(arow  + s*16);
      b0C[s] = *reinterpret_cast<const bf16x8*>(brow0 + ko + s*16);
      b1C[s] = *reinterpret_cast<const bf16x8*>(brow1 + ko + s*16);
    }
    #pragma unroll
    for (int t = 0; t < 8; ++t){
      if (t < 7){
        int m0 = (t+1)*64;
        #pragma unroll
        for (int s = 0; s < 4; ++s){
          aN[s]  = *reinterpret_cast<const bf16x8*>(arow  + m0 + s*16);
          b0N[s] = *reinterpret_cast<const bf16x8*>(brow0 + ko + m0 + s*16);
          b1N[s] = *reinterpret_cast<const bf16x8*>(brow1 + ko + m0 + s*16);
        }
      }
      #pragma unroll
      for (int s = 0; s < 4; ++s){
        acc0 = MFMA32(aC[s], b0C[s], acc0);
        acc1 = MFMA32(aC[s], b1C[s], acc1);
      }
      if (t < 7){
        #pragma unroll
        for (int s = 0; s < 4; ++s){ aC[s] = aN[s]; b0C[s] = b0N[s]; b1C[s] = b1N[s]; }
      }
    }

    // VT dump from 32x32 C-layout: col n = l&31, row j = (r&3)+8*(r>>2)+4*lh
    __syncthreads();                     // prev kk's VT reads sealed
    #pragma unroll
    for (int nt32 = 0; nt32 < 2; ++nt32){
      int nh = wn*64 + nt32*32 + l31;
      f32x16 av = nt32 ? acc1 : acc0;
      #pragma unroll
      for (int g = 0; g < 4; ++g){
        int jb = wjt*4 + g;
        bf16x4 pk;
        #pragma unroll
        for (int r = 0; r < 4; ++r) pk[r] = (bf16)av[g*4 + r];
        *reinterpret_cast<bf16x4*>(
            &VT[nh*128 + ((jb ^ (nh & 15)) << 3) + (lh << 2)]) = pk;
      }
    }
    __syncthreads();                     // all dumps visible

    // cheb contraction (R9 mapping): wave -> t_out = w>>2, n-grp = w&3
    #pragma unroll
    for (int ks2 = 0; ks2 < 2; ++ks2){
      bf16x8 bc[4];
      #pragma unroll
      for (int cf = 0; cf < 4; ++cf)
        bc[cf] = *reinterpret_cast<const bf16x8*>(
            cp + (((kk*2 + ks2)*4 + cf)*64 + l)*8);
      #pragma unroll
      for (int h = 0; h < 2; ++h){
        int nh = h*64 + (w & 3)*16 + l15;
        int jb = (w >> 2)*8 + ks2*4 + lg;
        bf16x8 a2 = *reinterpret_cast<const bf16x8*>(
            &VT[nh*128 + ((jb ^ (nh & 15)) << 3)]);
        #pragma unroll
        for (int cf = 0; cf < 4; ++cf)
          acc2[h][cf] = MFMA16(a2, bc[cf], acc2[h][cf]);
      }
    }
  }

  __syncthreads();                      // all contraction reads done before SP
  // epilogue: SP[row=(t_out*128+n)][o] = acc2 + cheb_b, then coalesced store
  bf16* SP = VT;
  float cbv[4];
  #pragma unroll
  for (int cf = 0; cf < 4; ++cf) cbv[cf] = cb[cf*16 + l15];
  int b = jt >> 5, t0 = (jt & 31)*2;
  #pragma unroll
  for (int h = 0; h < 2; ++h){
    int rowb = (w >> 2)*128 + h*64 + (w & 3)*16 + lg*4;
    #pragma unroll
    for (int cf = 0; cf < 4; ++cf){
      int o = cf*16 + l15;
      #pragma unroll
      for (int r = 0; r < 4; ++r)
        SP[(rowb + r)*64 + o] = (bf16)(acc2[h][cf][r] + cbv[cf]);
    }
  }
  __syncthreads();
  #pragma unroll
  for (int q = 0; q < 4; ++q){
    int flat = q*512 + tid;             // 2048 chunks of 8 elems
    int row = flat >> 3, oc = (flat & 7)*8;
    int tl = row >> 7, n = row & 127;
    bf16x8 vv = *reinterpret_cast<const bf16x8*>(&SP[row*64 + oc]);
    *reinterpret_cast<bf16x8*>(
        &spm[(((size_t)b*512 + N0 + n)*64 + (t0 + tl))*64 + oc]) = vv;
  }
}

// ---------------- fusion: gate/res MFMA + combine; writes bf16 out_pre -----
__global__ __launch_bounds__(256,4) void k_fusion(const bf16* __restrict__ spm,
    const bf16* __restrict__ t2, const bf16* __restrict__ xlb,
    const bf16* __restrict__ gp, const bf16* __restrict__ rp,
    const float* __restrict__ sc2, const float* __restrict__ sh2,
    const float* __restrict__ gateb, bf16* __restrict__ pre,
    float* __restrict__ part){
  int tid = threadIdx.x, w = tid >> 6, l = tid & 63, l15 = l & 15, lg = l >> 4;
  int blk = blockIdx.x;
  int b = blk >> 9, n = blk & 511;
  size_t rowbase = (size_t)blk * 64;
  int t = w*16 + l15;
  f32x4 ag[4] = {}, ar[4] = {};
  #pragma unroll
  for (int ks = 0; ks < 4; ++ks){                 // gate: K=128 = [spatial|t2bn]
    bf16x8 a;
    if (ks < 2){
      a = *reinterpret_cast<const bf16x8*>(spm + (rowbase + t)*64 + ks*32 + lg*8);
    } else {
      int i0 = (ks-2)*32 + lg*8;
      bf16x8 raw = *reinterpret_cast<const bf16x8*>(t2 + (rowbase + t)*64 + i0);
      #pragma unroll
      for (int e = 0; e < 8; ++e){
        float f = (float)raw[e]*sc2[i0+e] + sh2[i0+e];
        a[e] = (bf16)fmaxf(f, 0.f);
      }
    }
    #pragma unroll
    for (int cf = 0; cf < 4; ++cf){
      bf16x8 bfr = *reinterpret_cast<const bf16x8*>(gp + ((ks*4 + cf)*64 + l)*8);
      ag[cf] = MFMA16(a, bfr, ag[cf]);
    }
  }
  #pragma unroll
  for (int ks = 0; ks < 2; ++ks){                 // res: K=64 on x
    bf16x8 a = *reinterpret_cast<const bf16x8*>(xlb + (rowbase + t)*64 + ks*32 + lg*8);
    #pragma unroll
    for (int cf = 0; cf < 4; ++cf){
      bf16x8 bfr = *reinterpret_cast<const bf16x8*>(rp + ((ks*4 + cf)*64 + l)*8);
      ar[cf] = MFMA16(a, bfr, ar[cf]);
    }
  }
  __shared__ float ssum[4][4][16], ssq[4][4][16];
  int tb = w*16 + lg*4;
  #pragma unroll
  for (int cf = 0; cf < 4; ++cf){
    int o = cf*16 + l15;
    float gb = gateb[o], sco = sc2[o], sho = sh2[o];
    float s = 0.f, q = 0.f;
    bf16x4 ov;
    #pragma unroll
    for (int r = 0; r < 4; ++r){
      size_t row = rowbase + tb + r;
      float z = ag[cf][r] + gb;
      float g = 1.f/(1.f + __expf(-z));
      float spv = (float)spm[row*64 + o];
      float tv  = (float)t2[row*64 + o];
      tv = fmaxf(tv*sco + sho, 0.f);
      float val = g*spv + (1.f - g)*tv + ar[cf][r];
      ov[r] = (bf16)val;
      s += val; q += val*val;
    }
    *reinterpret_cast<bf16x4*>(pre + (((size_t)b*64 + o)*512 + n)*64 + tb) = ov;
    s += __shfl_xor(s, 16); s += __shfl_xor(s, 32);
    q += __shfl_xor(q, 16); q += __shfl_xor(q, 32);
    if (lg == 0){ ssum[w][cf][l15] = s; ssq[w][cf][l15] = q; }
  }
  __syncthreads();
  if (tid < 64){
    int cf = tid >> 4, c = tid & 15;
    float s = ssum[0][cf][c]+ssum[1][cf][c]+ssum[2][cf][c]+ssum[3][cf][c];
    float q = ssq[0][cf][c]+ssq[1][cf][c]+ssq[2][cf][c]+ssq[3][cf][c];
    part[(size_t)blk*128 + tid*2]     = s;
    part[(size_t)blk*128 + tid*2 + 1] = q;
  }
}

// ---------------- BN3: read bf16 out_pre, write fp32 d_out ------------------
__global__ __launch_bounds__(256) void k_bn3(const bf16* __restrict__ pre,
    float* __restrict__ out,
    const float* __restrict__ sc, const float* __restrict__ sh){
  size_t total8 = (size_t)BB*CC*NN*TT/8;
  for (size_t i8 = (size_t)blockIdx.x*256 + threadIdx.x; i8 < total8;
       i8 += (size_t)gridDim.x*256){
    bf16x8 v = reinterpret_cast<const bf16x8*>(pre)[i8];
    int o = (int)(i8 >> 12) & 63;                  // n*t = 32768 per (b,o)
    float a = sc[o], bsh = sh[o];
    float4 r0, r1;
    r0.x = (float)v[0]*a + bsh; r0.y = (float)v[1]*a + bsh;
    r0.z = (float)v[2]*a + bsh; r0.w = (float)v[3]*a + bsh;
    r1.x = (float)v[4]*a + bsh; r1.y = (float)v[5]*a + bsh;
    r1.z = (float)v[6]*a + bsh; r1.w = (float)v[7]*a + bsh;
    reinterpret_cast<float4*>(out)[i8*2]     = r0;
    reinterpret_cast<float4*>(out)[i8*2 + 1] = r1;
  }
}

extern "C" void kernel_launch(void* const* d_in, const int* in_sizes, int n_in,
                              void* d_out, int out_size, void* d_ws, size_t ws_size,
                              hipStream_t stream){
  (void)in_sizes; (void)n_in; (void)out_size; (void)ws_size;
  const float* x   = (const float*)d_in[0];
  const float* adj = (const float*)d_in[1];
  const float* cw  = (const float*)d_in[2];
  const float* cb  = (const float*)d_in[3];
  const float* w1  = (const float*)d_in[4];
  // d_in[5] = b1 (cancels in BN1)
  const float* g1  = (const float*)d_in[6];
  const float* be1 = (const float*)d_in[7];
  const float* w2  = (const float*)d_in[8];
  // d_in[9] = b2 (cancels in BN2)
  const float* g2  = (const float*)d_in[10];
  const float* be2 = (const float*)d_in[11];
  const float* gw  = (const float*)d_in[12];
  const float* gb  = (const float*)d_in[13];
  const float* rw  = (const float*)d_in[14];
  // d_in[15] = res_b (cancels in BN3)
  const float* g3  = (const float*)d_in[16];
  const float* be3 = (const float*)d_in[17];
  float* out = (float*)d_out;

  char* ws = (char*)d_ws;
  size_t off = 0;
  auto alloc = [&](size_t bytes)->char*{
    char* p = ws + off; off += (bytes + 255) & ~(size_t)255; return p;
  };
  bf16* xlb  = (bf16*)alloc((size_t)PP*64*2);        // 67MB channel-last x
  bf16* xmt  = (bf16*)alloc((size_t)PP*64*2);        // 67MB; reused as out_pre
  bf16* t1   = (bf16*)alloc((size_t)PP*64*2);        // 67MB; reused as spm
  bf16* t2   = (bf16*)alloc((size_t)PP*64*2);        // 67MB
  bf16* spm  = t1;                                   // alias (t1 dead after conv2)
  bf16* pre  = xmt;                                  // alias (xmt dead after gemm1)
  bf16* adjb = (bf16*)alloc((size_t)KCH*512*512*2);
  bf16* w1p  = (bf16*)alloc(6*2048*2);
  bf16* w2p  = (bf16*)alloc(6*2048*2);
  bf16* cp   = (bf16*)alloc(6*2048*2);
  bf16* gp   = (bf16*)alloc(4*2048*2);
  bf16* rp   = (bf16*)alloc(2*2048*2);
  float* part = (float*)alloc((size_t)8192*128*4);   // shared partials (sequential)
  float* s1sc = (float*)alloc(256); float* s1sh = (float*)alloc(256);
  float* s2sc = (float*)alloc(256); float* s2sh = (float*)alloc(256);
  float* s3sc = (float*)alloc(256); float* s3sh = (float*)alloc(256);

  k_prep <<<dim3(3168), dim3(256), 0, stream>>>(adj, w1, w2, cw, gw, rw,
                                                adjb, w1p, w2p, cp, gp, rp);
  k_xprep<<<dim3(1024), dim3(256), 0, stream>>>(x, xlb, xmt);

  k_conv <<<dim3(8192), dim3(256), 0, stream>>>(xlb, w1p, t1, part, nullptr, nullptr);
  k_stats<<<dim3(64),   dim3(256), 0, stream>>>(part, 8192, g1, be1, s1sc, s1sh);
  k_conv <<<dim3(8192), dim3(256), 0, stream>>>(t1, w2p, t2, part, s1sc, s1sh);
  k_stats<<<dim3(64),   dim3(256), 0, stream>>>(part, 8192, g2, be2, s2sc, s2sh);

  k_gemm1<<<dim3(2048), dim3(512), 0, stream>>>(xmt, adjb, cp, cb, spm);

  k_fusion<<<dim3(8192), dim3(256), 0, stream>>>(spm, t2, xlb, gp, rp,
                                                 s2sc, s2sh, gb, pre, part);
  k_stats<<<dim3(64),   dim3(256), 0, stream>>>(part, 8192, g3, be3, s3sc, s3sh);
  k_bn3  <<<dim3(2048), dim3(256), 0, stream>>>(pre, out, s3sc, s3sh);
}

// Round 12
// 557.100 us; speedup vs baseline: 1.4453x; 1.4453x over previous
//
#include <hip/hip_runtime.h>
#include <hip/hip_bf16.h>
#include <cstdint>

// Problem dims
#define BB 16
#define CC 64
#define NN 512
#define TT 64
#define KCH 3
#define PP (BB*NN*TT)      // 524288 points
#define EPSB 1e-5f

typedef __bf16 bf16;
typedef __bf16 bf16x8 __attribute__((ext_vector_type(8)));
typedef __bf16 bf16x4 __attribute__((ext_vector_type(4)));
typedef float  f32x4  __attribute__((ext_vector_type(4)));

#define MFMA16(A,Bv,Cv) __builtin_amdgcn_mfma_f32_16x16x32_bf16((A),(Bv),(Cv),0,0,0)

__device__ __forceinline__ void gload_lds16(const bf16* g, bf16* l){
  __builtin_amdgcn_global_load_lds(
      (const __attribute__((address_space(1))) void*)g,
      (__attribute__((address_space(3))) void*)l, 16, 0, 0);
}

// ---------------- prep (merged): adjb transpose + weight fragment prep -----
__global__ __launch_bounds__(256) void k_prep(const float* __restrict__ adj,
    const float* __restrict__ w1, const float* __restrict__ w2,
    const float* __restrict__ cw, const float* __restrict__ gw,
    const float* __restrict__ rw, bf16* __restrict__ adjb,
    bf16* __restrict__ w1p, bf16* __restrict__ w2p, bf16* __restrict__ cp,
    bf16* __restrict__ gp, bf16* __restrict__ rp){
  int blk = blockIdx.x, tid = threadIdx.x;
  if (blk < 3072){
    int idx = blk*256 + tid;
    int m = idx & 511, n = (idx >> 9) & 511, k = idx >> 18;
    adjb[idx] = (bf16)adj[((size_t)(k*512 + m))*512 + n];
    return;
  }
  int e0 = (blk - 3072)*256 + tid;                  // [0, 24576)
  if (e0 < 12288){                                  // K=192 groups (conv & cheb)
    int e = e0;
    int j = e&7, lane = (e>>3)&63, cf = (e>>9)&3, ks = e>>11;
    int k = ks*32 + (lane>>4)*8 + j, col = cf*16 + (lane&15);
    int kk = k >> 6, i = k & 63;
    w1p[e] = (bf16)w1[(col*64 + i)*3 + kk];
    w2p[e] = (bf16)w2[(col*64 + i)*3 + kk];
    cp[e]  = (bf16)cw[((size_t)kk*64 + i)*64 + col];
  } else if (e0 < 20480){                           // K=128 (gate)
    int e = e0 - 12288;
    int j = e&7, lane = (e>>3)&63, cf = (e>>9)&3, ks = e>>11;
    int k = ks*32 + (lane>>4)*8 + j, col = cf*16 + (lane&15);
    gp[e] = (bf16)gw[col*128 + k];
  } else {                                          // K=64 (res)
    int e = e0 - 20480;
    int j = e&7, lane = (e>>3)&63, cf = (e>>9)&3, ks = e>>11;
    int k = ks*32 + (lane>>4)*8 + j, col = cf*16 + (lane&15);
    rp[e] = (bf16)rw[col*64 + k];
  }
}

// ---------------- fused x prep: one read of x -> xlb AND xmt ----------------
__global__ __launch_bounds__(256) void k_xprep(const float* __restrict__ x,
    bf16* __restrict__ xlb, bf16* __restrict__ xmt){
  __shared__ bf16 T[32768];               // 64KB
  int bid = blockIdx.x;
  int b = bid >> 6, i0 = ((bid >> 3) & 7)*8, n0 = (bid & 7)*64;
  int tid = threadIdx.x;
  #pragma unroll 4
  for (int it = 0; it < 32; ++it){
    int flat = it*256 + tid;              // [0,8192)
    int t4 = flat & 15, n = (flat >> 4) & 63, i = flat >> 10;
    float4 v = *reinterpret_cast<const float4*>(
        x + ((size_t)((b*64 + i0 + i)*512) + (n0 + n))*64 + t4*4);
    int s = t4 ^ ((n + 2*i) & 15);
    bf16x4 pk; pk[0]=(bf16)v.x; pk[1]=(bf16)v.y; pk[2]=(bf16)v.z; pk[3]=(bf16)v.w;
    *reinterpret_cast<bf16x4*>(&T[(i*64 + n)*64 + s*4]) = pk;
  }
  __syncthreads();
  // xmt emission
  #pragma unroll 4
  for (int it = 0; it < 16; ++it){
    int flat = it*256 + tid;              // [0,4096)
    int mc = flat & 7, i = (flat >> 3) & 7, t = flat >> 6;
    bf16x8 o;
    #pragma unroll
    for (int e = 0; e < 8; ++e){
      int m = mc*8 + e;
      int s = (t >> 2) ^ ((m + 2*i) & 15);
      o[e] = T[(i*64 + m)*64 + s*4 + (t & 3)];
    }
    *reinterpret_cast<bf16x8*>(
        &xmt[((size_t)((b*64 + t)*64) + i0 + i)*512 + n0 + mc*8]) = o;
  }
  // xlb emission
  #pragma unroll 4
  for (int it = 0; it < 16; ++it){
    int flat = it*256 + tid;              // [0,4096)
    int t = flat & 63, n = flat >> 6;
    bf16x8 o;
    #pragma unroll
    for (int e = 0; e < 8; ++e){
      int s = (t >> 2) ^ ((n + 2*e) & 15);
      o[e] = T[(e*64 + n)*64 + s*4 + (t & 3)];
    }
    *reinterpret_cast<bf16x8*>(
        &xlb[(((size_t)b*512 + n0 + n)*64 + t)*64 + i0]) = o;
  }
}

// ---------------- temporal conv (1x3) as tall GEMM; optional BN+relu on load
__global__ __launch_bounds__(256,4) void k_conv(const bf16* __restrict__ in,
    const bf16* __restrict__ wp, bf16* __restrict__ outp, float* __restrict__ part,
    const float* __restrict__ sc, const float* __restrict__ sh){
  int tid = threadIdx.x, w = tid >> 6, l = tid & 63, l15 = l & 15, lg = l >> 4;
  int blk = blockIdx.x;
  size_t rowbase = (size_t)blk * 64;
  const bf16* xr = in + rowbase * 64;
  int t = w*16 + l15;
  f32x4 acc[4] = {};
  #pragma unroll
  for (int ks = 0; ks < 6; ++ks){
    int dt = ks >> 1, kh = ks & 1;
    int ts = t + dt - 1;
    bf16x8 a = {};
    if (ts >= 0 && ts < 64){
      a = *reinterpret_cast<const bf16x8*>(xr + ts*64 + kh*32 + lg*8);
      if (sc){                                  // BN1+relu applied on load
        int i0 = kh*32 + lg*8;
        #pragma unroll
        for (int e = 0; e < 8; ++e){
          float f = (float)a[e]*sc[i0+e] + sh[i0+e];
          a[e] = (bf16)fmaxf(f, 0.f);
        }
      }
    }
    #pragma unroll
    for (int cf = 0; cf < 4; ++cf){
      bf16x8 bfr = *reinterpret_cast<const bf16x8*>(wp + ((ks*4 + cf)*64 + l)*8);
      acc[cf] = MFMA16(a, bfr, acc[cf]);
    }
  }
  __shared__ float ssum[4][4][16], ssq[4][4][16];
  #pragma unroll
  for (int cf = 0; cf < 4; ++cf){
    int o = cf*16 + l15;
    float s = 0.f, q = 0.f;
    #pragma unroll
    for (int r = 0; r < 4; ++r){
      float vv = acc[cf][r];
      int to = w*16 + lg*4 + r;
      outp[(rowbase + to)*64 + o] = (bf16)vv;
      s += vv; q += vv*vv;
    }
    s += __shfl_xor(s, 16); s += __shfl_xor(s, 32);
    q += __shfl_xor(q, 16); q += __shfl_xor(q, 32);
    if (lg == 0){ ssum[w][cf][l15] = s; ssq[w][cf][l15] = q; }
  }
  __syncthreads();
  if (tid < 64){
    int cf = tid >> 4, c = tid & 15;
    float s = ssum[0][cf][c]+ssum[1][cf][c]+ssum[2][cf][c]+ssum[3][cf][c];
    float q = ssq[0][cf][c]+ssq[1][cf][c]+ssq[2][cf][c]+ssq[3][cf][c];
    part[(size_t)blk*128 + tid*2]     = s;
    part[(size_t)blk*128 + tid*2 + 1] = q;
  }
}

// ---------------- BN stats finalize: partials -> scale/shift ----------------
__global__ __launch_bounds__(256) void k_stats(const float* __restrict__ part, int nb,
    const float* __restrict__ g, const float* __restrict__ be,
    float* __restrict__ sc, float* __restrict__ sh){
  int c = blockIdx.x, tid = threadIdx.x;
  float s = 0.f, q = 0.f;
  for (int i = tid; i < nb; i += 256){
    s += part[(size_t)i*128 + c*2];
    q += part[(size_t)i*128 + c*2 + 1];
  }
  __shared__ float rs[256], rq[256];
  rs[tid] = s; rq[tid] = q; __syncthreads();
  for (int st = 128; st > 0; st >>= 1){
    if (tid < st){ rs[tid] += rs[tid+st]; rq[tid] += rq[tid+st]; }
    __syncthreads();
  }
  if (tid == 0){
    float cnt = (float)PP;
    float mean = rs[0]/cnt, var = rq[0]/cnt - mean*mean;
    float r = rsqrtf(var + EPSB);
    sc[c] = g[c]*r;
    sh[c] = be[c] - mean*g[c]*r;
  }
}

// ---------------- fused GEMM1+cheb: spm[(b,n,t)][o] ------------------------
// v11 (= v10 with the LDS pointer-array compile fix): 8-phase-class schedule
// (T2+T3+T4+T5). BM=256(j) x BN=128(n), BK=64, 8 waves (2Mx4N), 2 dbuf in one
// 96KB LDS array (A bufs @0/16384 elems, B bufs @32768/40960 elems). Per
// K-tile: 2 phases {stage 3 gloads || 10 ds_read || 16 MFMA + setprio};
// counted vmcnt(3) once per K-tile, never 0 mid-loop. Chunk swizzle c^=row&7
// (BK=64 -> 8 chunks -> 2-way, free). VT(64KB) aliases A-buf region at kk
// boundaries; cheb contraction into acc2 across kk; SP epilogue.
__global__ __launch_bounds__(512,2) void k_gemm1(const bf16* __restrict__ xmt,
    const bf16* __restrict__ adjb, const bf16* __restrict__ cp,
    const float* __restrict__ cb, bf16* __restrict__ spm){
  __shared__ __align__(16) bf16 LDS[49152];        // 96KB

  int tid = threadIdx.x, w = tid >> 6, l = tid & 63, l15 = l & 15, lg = l >> 4;
  int wm = w >> 2, wn2 = w & 3;

  // bijective XCD swizzle over 1024 blocks; nt innermost
  int orig = blockIdx.x;
  int wg = (orig & 7) * 128 + (orig >> 3);
  int jt = wg >> 2, nt = wg & 3;
  int J0 = jt*256, N0 = nt*128;

  const bf16* aglob = xmt + (size_t)J0*512;
  const bf16* bglob = adjb + (size_t)N0*512;

  // staging: thread -> (row srow within 64-row group, swizzled chunk scn)
  int srow = tid >> 3, scn = (tid & 7) ^ (srow & 7);
  size_t soff = (size_t)srow*512 + scn*8;

  // ds_read offsets (elements): colx shared by A and B (row&7 == l15&7)
  int colx[2];
  #pragma unroll
  for (int ks = 0; ks < 2; ++ks) colx[ks] = ((ks*4 + lg) ^ (l15 & 7))*8;
  int aoff[8], boff[2];
  #pragma unroll
  for (int jf = 0; jf < 8; ++jf) aoff[jf] = (wm*128 + jf*16 + l15)*64;
  #pragma unroll
  for (int nf = 0; nf < 2; ++nf) boff[nf] = (wn2*32 + nf*16 + l15)*64;

  f32x4 acc[8][2];
  f32x4 acc2[4][4] = {};

  for (int kk = 0; kk < 3; ++kk){
    const bf16* bko = bglob + (size_t)kk*262144;
    #pragma unroll
    for (int jf = 0; jf < 8; ++jf)
      #pragma unroll
      for (int nf = 0; nf < 2; ++nf)
        acc[jf][nf] = (f32x4){0.f,0.f,0.f,0.f};

    // prologue: stage kt0 fully (6 loads) into buf 0
    #pragma unroll
    for (int u = 0; u < 4; ++u)
      gload_lds16(aglob + soff + (size_t)u*32768, LDS + (u*512 + tid)*8);
    #pragma unroll
    for (int u = 0; u < 2; ++u)
      gload_lds16(bko + soff + (size_t)u*32768, LDS + 32768 + (u*512 + tid)*8);

    for (int kt = 0; kt < 8; ++kt){
      int buf = kt & 1, nbuf = buf ^ 1;
      bf16* Ab = LDS + buf*16384;
      bf16* Bb = LDS + 32768 + buf*8192;
      bf16* An = LDS + nbuf*16384;
      bf16* Bn = LDS + 32768 + nbuf*8192;
      int mnext = (kt+1)*64;
      #pragma unroll
      for (int ph = 0; ph < 2; ++ph){
        // stage 3 loads for kt+1
        if (kt < 7){
          if (ph == 0){
            gload_lds16(aglob + soff + 0*32768 + mnext, An + (0*512 + tid)*8);
            gload_lds16(aglob + soff + 1*32768 + mnext, An + (1*512 + tid)*8);
            gload_lds16(aglob + soff + 2*32768 + mnext, An + (2*512 + tid)*8);
          } else {
            gload_lds16(aglob + soff + 3*32768 + mnext, An + (3*512 + tid)*8);
            gload_lds16(bko + soff + 0*32768 + mnext, Bn + (0*512 + tid)*8);
            gload_lds16(bko + soff + 1*32768 + mnext, Bn + (1*512 + tid)*8);
          }
        }
        if (ph == 0){
          if (kt < 7) asm volatile("s_waitcnt vmcnt(3)" ::: "memory");
          else        asm volatile("s_waitcnt vmcnt(0)" ::: "memory");
        }
        __builtin_amdgcn_sched_barrier(0);
        __builtin_amdgcn_s_barrier();
        __builtin_amdgcn_sched_barrier(0);

        bf16x8 a[8], bfr[2];
        #pragma unroll
        for (int jf = 0; jf < 8; ++jf)
          a[jf] = *reinterpret_cast<const bf16x8*>(&Ab[aoff[jf] + colx[ph]]);
        #pragma unroll
        for (int nf = 0; nf < 2; ++nf)
          bfr[nf] = *reinterpret_cast<const bf16x8*>(&Bb[boff[nf] + colx[ph]]);

        __builtin_amdgcn_s_setprio(1);
        #pragma unroll
        for (int jf = 0; jf < 8; ++jf)
          #pragma unroll
          for (int nf = 0; nf < 2; ++nf)
            acc[jf][nf] = MFMA16(a[jf], bfr[nf], acc[jf][nf]);
        __builtin_amdgcn_s_setprio(0);

        asm volatile("s_waitcnt lgkmcnt(0)" ::: "memory");
        __builtin_amdgcn_sched_barrier(0);
        __builtin_amdgcn_s_barrier();
      }
    }

    // ---- kk boundary: dump V-tile into VT[n:128][j:256] (16B-granule XOR) --
    // VT = LDS bytes [0,65536) aliasing the A bufs (all A reads sealed above)
    char* VTb = (char*)LDS;
    #pragma unroll
    for (int jf = 0; jf < 8; ++jf){
      int jb = wm*128 + jf*16 + lg*4;
      int jc16 = jb >> 3, jlow = (jb >> 2) & 1;
      #pragma unroll
      for (int nf = 0; nf < 2; ++nf){
        int n = wn2*32 + nf*16 + l15;
        bf16x4 pk;
        #pragma unroll
        for (int r = 0; r < 4; ++r) pk[r] = (bf16)acc[jf][nf][r];
        *reinterpret_cast<bf16x4*>(
            VTb + n*512 + ((jc16 ^ (n & 31)) << 4) + (jlow << 3)) = pk;
      }
    }
    asm volatile("s_waitcnt lgkmcnt(0)" ::: "memory");
    __builtin_amdgcn_sched_barrier(0);
    __builtin_amdgcn_s_barrier();

    // ---- cheb contraction: wave w -> tloc = w>>1, n-half = (w&1)*64 --------
    {
      int tloc = w >> 1, nbase = (w & 1)*64;
      #pragma unroll
      for (int ks2 = 0; ks2 < 2; ++ks2){
        bf16x8 bc[4];
        #pragma unroll
        for (int cf = 0; cf < 4; ++cf)
          bc[cf] = *reinterpret_cast<const bf16x8*>(
              cp + (((kk*2 + ks2)*4 + cf)*64 + l)*8);
        #pragma unroll
        for (int rf2 = 0; rf2 < 4; ++rf2){
          int nloc = nbase + rf2*16 + l15;
          int jc16 = tloc*8 + ks2*4 + lg;
          bf16x8 a2 = *reinterpret_cast<const bf16x8*>(
              VTb + nloc*512 + ((jc16 ^ (nloc & 31)) << 4));
          #pragma unroll
          for (int cf = 0; cf < 4; ++cf)
            acc2[rf2][cf] = MFMA16(a2, bc[cf], acc2[rf2][cf]);
        }
      }
    }
    asm volatile("s_waitcnt lgkmcnt(0)" ::: "memory");
    __builtin_amdgcn_sched_barrier(0);
    __builtin_amdgcn_s_barrier();      // VT reads sealed before next kk stages
  }

  // ---- epilogue: SP[row=(tloc*128+nloc)][o] = acc2 + cheb_b ---------------
  bf16* SP = LDS;                       // 512 rows x 64 o = 64KB
  float cbv[4];
  #pragma unroll
  for (int cf = 0; cf < 4; ++cf) cbv[cf] = cb[cf*16 + l15];
  #pragma unroll
  for (int rf2 = 0; rf2 < 4; ++rf2){
    int rowb = w*64 + rf2*16 + lg*4;
    #pragma unroll
    for (int cf = 0; cf < 4; ++cf){
      int o = cf*16 + l15;
      #pragma unroll
      for (int r = 0; r < 4; ++r)
        SP[(rowb + r)*64 + o] = (bf16)(acc2[rf2][cf][r] + cbv[cf]);
    }
  }
  __syncthreads();
  int b = jt >> 4, t0 = (jt & 15)*4;
  #pragma unroll
  for (int q = 0; q < 8; ++q){
    int flat = q*512 + tid;             // 4096 chunks of 8 elems
    int row = flat >> 3, oc = (flat & 7)*8;
    int tloc2 = row >> 7, n = N0 + (row & 127);
    bf16x8 vv = *reinterpret_cast<const bf16x8*>(&SP[row*64 + oc]);
    *reinterpret_cast<bf16x8*>(
        &spm[(((size_t)b*512 + n)*64 + (t0 + tloc2))*64 + oc]) = vv;
  }
}

// ---------------- fusion: gate/res MFMA + combine; writes bf16 out_pre -----
__global__ __launch_bounds__(256,4) void k_fusion(const bf16* __restrict__ spm,
    const bf16* __restrict__ t2, const bf16* __restrict__ xlb,
    const bf16* __restrict__ gp, const bf16* __restrict__ rp,
    const float* __restrict__ sc2, const float* __restrict__ sh2,
    const float* __restrict__ gateb, bf16* __restrict__ pre,
    float* __restrict__ part){
  int tid = threadIdx.x, w = tid >> 6, l = tid & 63, l15 = l & 15, lg = l >> 4;
  int blk = blockIdx.x;
  int b = blk >> 9, n = blk & 511;
  size_t rowbase = (size_t)blk * 64;
  int t = w*16 + l15;
  f32x4 ag[4] = {}, ar[4] = {};
  #pragma unroll
  for (int ks = 0; ks < 4; ++ks){                 // gate: K=128 = [spatial|t2bn]
    bf16x8 a;
    if (ks < 2){
      a = *reinterpret_cast<const bf16x8*>(spm + (rowbase + t)*64 + ks*32 + lg*8);
    } else {
      int i0 = (ks-2)*32 + lg*8;
      bf16x8 raw = *reinterpret_cast<const bf16x8*>(t2 + (rowbase + t)*64 + i0);
      #pragma unroll
      for (int e = 0; e < 8; ++e){
        float f = (float)raw[e]*sc2[i0+e] + sh2[i0+e];
        a[e] = (bf16)fmaxf(f, 0.f);
      }
    }
    #pragma unroll
    for (int cf = 0; cf < 4; ++cf){
      bf16x8 bfr = *reinterpret_cast<const bf16x8*>(gp + ((ks*4 + cf)*64 + l)*8);
      ag[cf] = MFMA16(a, bfr, ag[cf]);
    }
  }
  #pragma unroll
  for (int ks = 0; ks < 2; ++ks){                 // res: K=64 on x
    bf16x8 a = *reinterpret_cast<const bf16x8*>(xlb + (rowbase + t)*64 + ks*32 + lg*8);
    #pragma unroll
    for (int cf = 0; cf < 4; ++cf){
      bf16x8 bfr = *reinterpret_cast<const bf16x8*>(rp + ((ks*4 + cf)*64 + l)*8);
      ar[cf] = MFMA16(a, bfr, ar[cf]);
    }
  }
  __shared__ float ssum[4][4][16], ssq[4][4][16];
  int tb = w*16 + lg*4;
  #pragma unroll
  for (int cf = 0; cf < 4; ++cf){
    int o = cf*16 + l15;
    float gb = gateb[o], sco = sc2[o], sho = sh2[o];
    float s = 0.f, q = 0.f;
    bf16x4 ov;
    #pragma unroll
    for (int r = 0; r < 4; ++r){
      size_t row = rowbase + tb + r;
      float z = ag[cf][r] + gb;
      float g = 1.f/(1.f + __expf(-z));
      float spv = (float)spm[row*64 + o];
      float tv  = (float)t2[row*64 + o];
      tv = fmaxf(tv*sco + sho, 0.f);
      float val = g*spv + (1.f - g)*tv + ar[cf][r];
      ov[r] = (bf16)val;
      s += val; q += val*val;
    }
    *reinterpret_cast<bf16x4*>(pre + (((size_t)b*64 + o)*512 + n)*64 + tb) = ov;
    s += __shfl_xor(s, 16); s += __shfl_xor(s, 32);
    q += __shfl_xor(q, 16); q += __shfl_xor(q, 32);
    if (lg == 0){ ssum[w][cf][l15] = s; ssq[w][cf][l15] = q; }
  }
  __syncthreads();
  if (tid < 64){
    int cf = tid >> 4, c = tid & 15;
    float s = ssum[0][cf][c]+ssum[1][cf][c]+ssum[2][cf][c]+ssum[3][cf][c];
    float q = ssq[0][cf][c]+ssq[1][cf][c]+ssq[2][cf][c]+ssq[3][cf][c];
    part[(size_t)blk*128 + tid*2]     = s;
    part[(size_t)blk*128 + tid*2 + 1] = q;
  }
}

// ---------------- BN3: read bf16 out_pre, write fp32 d_out ------------------
__global__ __launch_bounds__(256) void k_bn3(const bf16* __restrict__ pre,
    float* __restrict__ out,
    const float* __restrict__ sc, const float* __restrict__ sh){
  size_t total8 = (size_t)BB*CC*NN*TT/8;
  for (size_t i8 = (size_t)blockIdx.x*256 + threadIdx.x; i8 < total8;
       i8 += (size_t)gridDim.x*256){
    bf16x8 v = reinterpret_cast<const bf16x8*>(pre)[i8];
    int o = (int)(i8 >> 12) & 63;                  // n*t = 32768 per (b,o)
    float a = sc[o], bsh = sh[o];
    float4 r0, r1;
    r0.x = (float)v[0]*a + bsh; r0.y = (float)v[1]*a + bsh;
    r0.z = (float)v[2]*a + bsh; r0.w = (float)v[3]*a + bsh;
    r1.x = (float)v[4]*a + bsh; r1.y = (float)v[5]*a + bsh;
    r1.z = (float)v[6]*a + bsh; r1.w = (float)v[7]*a + bsh;
    reinterpret_cast<float4*>(out)[i8*2]     = r0;
    reinterpret_cast<float4*>(out)[i8*2 + 1] = r1;
  }
}

extern "C" void kernel_launch(void* const* d_in, const int* in_sizes, int n_in,
                              void* d_out, int out_size, void* d_ws, size_t ws_size,
                              hipStream_t stream){
  (void)in_sizes; (void)n_in; (void)out_size; (void)ws_size;
  const float* x   = (const float*)d_in[0];
  const float* adj = (const float*)d_in[1];
  const float* cw  = (const float*)d_in[2];
  const float* cb  = (const float*)d_in[3];
  const float* w1  = (const float*)d_in[4];
  // d_in[5] = b1 (cancels in BN1)
  const float* g1  = (const float*)d_in[6];
  const float* be1 = (const float*)d_in[7];
  const float* w2  = (const float*)d_in[8];
  // d_in[9] = b2 (cancels in BN2)
  const float* g2  = (const float*)d_in[10];
  const float* be2 = (const float*)d_in[11];
  const float* gw  = (const float*)d_in[12];
  const float* gb  = (const float*)d_in[13];
  const float* rw  = (const float*)d_in[14];
  // d_in[15] = res_b (cancels in BN3)
  const float* g3  = (const float*)d_in[16];
  const float* be3 = (const float*)d_in[17];
  float* out = (float*)d_out;

  char* ws = (char*)d_ws;
  size_t off = 0;
  auto alloc = [&](size_t bytes)->char*{
    char* p = ws + off; off += (bytes + 255) & ~(size_t)255; return p;
  };
  bf16* xlb  = (bf16*)alloc((size_t)PP*64*2);        // 67MB channel-last x
  bf16* xmt  = (bf16*)alloc((size_t)PP*64*2);        // 67MB; reused as out_pre
  bf16* t1   = (bf16*)alloc((size_t)PP*64*2);        // 67MB; reused as spm
  bf16* t2   = (bf16*)alloc((size_t)PP*64*2);        // 67MB
  bf16* spm  = t1;                                   // alias (t1 dead after conv2)
  bf16* pre  = xmt;                                  // alias (xmt dead after gemm1)
  bf16* adjb = (bf16*)alloc((size_t)KCH*512*512*2);
  bf16* w1p  = (bf16*)alloc(6*2048*2);
  bf16* w2p  = (bf16*)alloc(6*2048*2);
  bf16* cp   = (bf16*)alloc(6*2048*2);
  bf16* gp   = (bf16*)alloc(4*2048*2);
  bf16* rp   = (bf16*)alloc(2*2048*2);
  float* part = (float*)alloc((size_t)8192*128*4);   // shared partials (sequential)
  float* s1sc = (float*)alloc(256); float* s1sh = (float*)alloc(256);
  float* s2sc = (float*)alloc(256); float* s2sh = (float*)alloc(256);
  float* s3sc = (float*)alloc(256); float* s3sh = (float*)alloc(256);

  k_prep <<<dim3(3168), dim3(256), 0, stream>>>(adj, w1, w2, cw, gw, rw,
                                                adjb, w1p, w2p, cp, gp, rp);
  k_xprep<<<dim3(1024), dim3(256), 0, stream>>>(x, xlb, xmt);

  k_conv <<<dim3(8192), dim3(256), 0, stream>>>(xlb, w1p, t1, part, nullptr, nullptr);
  k_stats<<<dim3(64),   dim3(256), 0, stream>>>(part, 8192, g1, be1, s1sc, s1sh);
  k_conv <<<dim3(8192), dim3(256), 0, stream>>>(t1, w2p, t2, part, s1sc, s1sh);
  k_stats<<<dim3(64),   dim3(256), 0, stream>>>(part, 8192, g2, be2, s2sc, s2sh);

  k_gemm1<<<dim3(1024), dim3(512), 0, stream>>>(xmt, adjb, cp, cb, spm);

  k_fusion<<<dim3(8192), dim3(256), 0, stream>>>(spm, t2, xlb, gp, rp,
                                                 s2sc, s2sh, gb, pre, part);
  k_stats<<<dim3(64),   dim3(256), 0, stream>>>(part, 8192, g3, be3, s3sc, s3sh);
  k_bn3  <<<dim3(2048), dim3(256), 0, stream>>>(pre, out, s3sc, s3sh);
}

// Round 13
// 554.195 us; speedup vs baseline: 1.4529x; 1.0052x over previous
//
#include <hip/hip_runtime.h>
#include <hip/hip_bf16.h>
#include <cstdint>

// Problem dims
#define BB 16
#define CC 64
#define NN 512
#define TT 64
#define KCH 3
#define PP (BB*NN*TT)      // 524288 points
#define EPSB 1e-5f

typedef __bf16 bf16;
typedef __bf16 bf16x8 __attribute__((ext_vector_type(8)));
typedef __bf16 bf16x4 __attribute__((ext_vector_type(4)));
typedef float  f32x4  __attribute__((ext_vector_type(4)));

#define MFMA16(A,Bv,Cv) __builtin_amdgcn_mfma_f32_16x16x32_bf16((A),(Bv),(Cv),0,0,0)

__device__ __forceinline__ void gload_lds16(const bf16* g, bf16* l){
  __builtin_amdgcn_global_load_lds(
      (const __attribute__((address_space(1))) void*)g,
      (__attribute__((address_space(3))) void*)l, 16, 0, 0);
}

// ---------------- prep (merged): adjb transpose + weight fragment prep -----
__global__ __launch_bounds__(256) void k_prep(const float* __restrict__ adj,
    const float* __restrict__ w1, const float* __restrict__ w2,
    const float* __restrict__ cw, const float* __restrict__ gw,
    const float* __restrict__ rw, bf16* __restrict__ adjb,
    bf16* __restrict__ w1p, bf16* __restrict__ w2p, bf16* __restrict__ cp,
    bf16* __restrict__ gp, bf16* __restrict__ rp){
  int blk = blockIdx.x, tid = threadIdx.x;
  if (blk < 3072){
    int idx = blk*256 + tid;
    int m = idx & 511, n = (idx >> 9) & 511, k = idx >> 18;
    adjb[idx] = (bf16)adj[((size_t)(k*512 + m))*512 + n];
    return;
  }
  int e0 = (blk - 3072)*256 + tid;                  // [0, 24576)
  if (e0 < 12288){                                  // K=192 groups (conv & cheb)
    int e = e0;
    int j = e&7, lane = (e>>3)&63, cf = (e>>9)&3, ks = e>>11;
    int k = ks*32 + (lane>>4)*8 + j, col = cf*16 + (lane&15);
    int kk = k >> 6, i = k & 63;
    w1p[e] = (bf16)w1[(col*64 + i)*3 + kk];
    w2p[e] = (bf16)w2[(col*64 + i)*3 + kk];
    cp[e]  = (bf16)cw[((size_t)kk*64 + i)*64 + col];
  } else if (e0 < 20480){                           // K=128 (gate)
    int e = e0 - 12288;
    int j = e&7, lane = (e>>3)&63, cf = (e>>9)&3, ks = e>>11;
    int k = ks*32 + (lane>>4)*8 + j, col = cf*16 + (lane&15);
    gp[e] = (bf16)gw[col*128 + k];
  } else {                                          // K=64 (res)
    int e = e0 - 20480;
    int j = e&7, lane = (e>>3)&63, cf = (e>>9)&3, ks = e>>11;
    int k = ks*32 + (lane>>4)*8 + j, col = cf*16 + (lane&15);
    rp[e] = (bf16)rw[col*64 + k];
  }
}

// ---------------- fused x prep: one read of x -> xlb AND xmt ----------------
__global__ __launch_bounds__(256) void k_xprep(const float* __restrict__ x,
    bf16* __restrict__ xlb, bf16* __restrict__ xmt){
  __shared__ bf16 T[32768];               // 64KB
  int bid = blockIdx.x;
  int b = bid >> 6, i0 = ((bid >> 3) & 7)*8, n0 = (bid & 7)*64;
  int tid = threadIdx.x;
  #pragma unroll 4
  for (int it = 0; it < 32; ++it){
    int flat = it*256 + tid;              // [0,8192)
    int t4 = flat & 15, n = (flat >> 4) & 63, i = flat >> 10;
    float4 v = *reinterpret_cast<const float4*>(
        x + ((size_t)((b*64 + i0 + i)*512) + (n0 + n))*64 + t4*4);
    int s = t4 ^ ((n + 2*i) & 15);
    bf16x4 pk; pk[0]=(bf16)v.x; pk[1]=(bf16)v.y; pk[2]=(bf16)v.z; pk[3]=(bf16)v.w;
    *reinterpret_cast<bf16x4*>(&T[(i*64 + n)*64 + s*4]) = pk;
  }
  __syncthreads();
  // xmt emission
  #pragma unroll 4
  for (int it = 0; it < 16; ++it){
    int flat = it*256 + tid;              // [0,4096)
    int mc = flat & 7, i = (flat >> 3) & 7, t = flat >> 6;
    bf16x8 o;
    #pragma unroll
    for (int e = 0; e < 8; ++e){
      int m = mc*8 + e;
      int s = (t >> 2) ^ ((m + 2*i) & 15);
      o[e] = T[(i*64 + m)*64 + s*4 + (t & 3)];
    }
    *reinterpret_cast<bf16x8*>(
        &xmt[((size_t)((b*64 + t)*64) + i0 + i)*512 + n0 + mc*8]) = o;
  }
  // xlb emission
  #pragma unroll 4
  for (int it = 0; it < 16; ++it){
    int flat = it*256 + tid;              // [0,4096)
    int t = flat & 63, n = flat >> 6;
    bf16x8 o;
    #pragma unroll
    for (int e = 0; e < 8; ++e){
      int s = (t >> 2) ^ ((n + 2*e) & 15);
      o[e] = T[(e*64 + n)*64 + s*4 + (t & 3)];
    }
    *reinterpret_cast<bf16x8*>(
        &xlb[(((size_t)b*512 + n0 + n)*64 + t)*64 + i0]) = o;
  }
}

// ---------------- temporal conv (1x3) as tall GEMM; optional BN+relu on load
__global__ __launch_bounds__(256,4) void k_conv(const bf16* __restrict__ in,
    const bf16* __restrict__ wp, bf16* __restrict__ outp, float* __restrict__ part,
    const float* __restrict__ sc, const float* __restrict__ sh){
  int tid = threadIdx.x, w = tid >> 6, l = tid & 63, l15 = l & 15, lg = l >> 4;
  int blk = blockIdx.x;
  size_t rowbase = (size_t)blk * 64;
  const bf16* xr = in + rowbase * 64;
  int t = w*16 + l15;
  f32x4 acc[4] = {};
  #pragma unroll
  for (int ks = 0; ks < 6; ++ks){
    int dt = ks >> 1, kh = ks & 1;
    int ts = t + dt - 1;
    bf16x8 a = {};
    if (ts >= 0 && ts < 64){
      a = *reinterpret_cast<const bf16x8*>(xr + ts*64 + kh*32 + lg*8);
      if (sc){                                  // BN1+relu applied on load
        int i0 = kh*32 + lg*8;
        #pragma unroll
        for (int e = 0; e < 8; ++e){
          float f = (float)a[e]*sc[i0+e] + sh[i0+e];
          a[e] = (bf16)fmaxf(f, 0.f);
        }
      }
    }
    #pragma unroll
    for (int cf = 0; cf < 4; ++cf){
      bf16x8 bfr = *reinterpret_cast<const bf16x8*>(wp + ((ks*4 + cf)*64 + l)*8);
      acc[cf] = MFMA16(a, bfr, acc[cf]);
    }
  }
  __shared__ float ssum[4][4][16], ssq[4][4][16];
  #pragma unroll
  for (int cf = 0; cf < 4; ++cf){
    int o = cf*16 + l15;
    float s = 0.f, q = 0.f;
    #pragma unroll
    for (int r = 0; r < 4; ++r){
      float vv = acc[cf][r];
      int to = w*16 + lg*4 + r;
      outp[(rowbase + to)*64 + o] = (bf16)vv;
      s += vv; q += vv*vv;
    }
    s += __shfl_xor(s, 16); s += __shfl_xor(s, 32);
    q += __shfl_xor(q, 16); q += __shfl_xor(q, 32);
    if (lg == 0){ ssum[w][cf][l15] = s; ssq[w][cf][l15] = q; }
  }
  __syncthreads();
  if (tid < 64){
    int cf = tid >> 4, c = tid & 15;
    float s = ssum[0][cf][c]+ssum[1][cf][c]+ssum[2][cf][c]+ssum[3][cf][c];
    float q = ssq[0][cf][c]+ssq[1][cf][c]+ssq[2][cf][c]+ssq[3][cf][c];
    part[(size_t)blk*128 + tid*2]     = s;
    part[(size_t)blk*128 + tid*2 + 1] = q;
  }
}

// ---------------- BN stats finalize: partials -> scale/shift ----------------
__global__ __launch_bounds__(256) void k_stats(const float* __restrict__ part, int nb,
    const float* __restrict__ g, const float* __restrict__ be,
    float* __restrict__ sc, float* __restrict__ sh){
  int c = blockIdx.x, tid = threadIdx.x;
  float s = 0.f, q = 0.f;
  for (int i = tid; i < nb; i += 256){
    s += part[(size_t)i*128 + c*2];
    q += part[(size_t)i*128 + c*2 + 1];
  }
  __shared__ float rs[256], rq[256];
  rs[tid] = s; rq[tid] = q; __syncthreads();
  for (int st = 128; st > 0; st >>= 1){
    if (tid < st){ rs[tid] += rs[tid+st]; rq[tid] += rq[tid+st]; }
    __syncthreads();
  }
  if (tid == 0){
    float cnt = (float)PP;
    float mean = rs[0]/cnt, var = rq[0]/cnt - mean*mean;
    float r = rsqrtf(var + EPSB);
    sc[c] = g[c]*r;
    sh[c] = be[c] - mean*g[c]*r;
  }
}

// ---------------- fused GEMM1+cheb: spm[(b,n,t)][o] ------------------------
// v12 = v11 with __launch_bounds__(512,1): LDS (96KB) already caps us at
// 1 block/CU, so the (512,2) VGPR cap (128) only caused ~53MB/dispatch of
// scratch spill traffic (R12: WRITE 65->100MB). Lifting the cap removes the
// spills at zero occupancy cost. Schedule unchanged (T2+T3+T4+T5).
__global__ __launch_bounds__(512,1) void k_gemm1(const bf16* __restrict__ xmt,
    const bf16* __restrict__ adjb, const bf16* __restrict__ cp,
    const float* __restrict__ cb, bf16* __restrict__ spm){
  __shared__ __align__(16) bf16 LDS[49152];        // 96KB

  int tid = threadIdx.x, w = tid >> 6, l = tid & 63, l15 = l & 15, lg = l >> 4;
  int wm = w >> 2, wn2 = w & 3;

  // bijective XCD swizzle over 1024 blocks; nt innermost
  int orig = blockIdx.x;
  int wg = (orig & 7) * 128 + (orig >> 3);
  int jt = wg >> 2, nt = wg & 3;
  int J0 = jt*256, N0 = nt*128;

  const bf16* aglob = xmt + (size_t)J0*512;
  const bf16* bglob = adjb + (size_t)N0*512;

  // staging: thread -> (row srow within 64-row group, swizzled chunk scn)
  int srow = tid >> 3, scn = (tid & 7) ^ (srow & 7);
  size_t soff = (size_t)srow*512 + scn*8;

  // ds_read offsets (elements): colx shared by A and B (row&7 == l15&7)
  int colx[2];
  #pragma unroll
  for (int ks = 0; ks < 2; ++ks) colx[ks] = ((ks*4 + lg) ^ (l15 & 7))*8;
  int aoff[8], boff[2];
  #pragma unroll
  for (int jf = 0; jf < 8; ++jf) aoff[jf] = (wm*128 + jf*16 + l15)*64;
  #pragma unroll
  for (int nf = 0; nf < 2; ++nf) boff[nf] = (wn2*32 + nf*16 + l15)*64;

  f32x4 acc[8][2];
  f32x4 acc2[4][4] = {};

  for (int kk = 0; kk < 3; ++kk){
    const bf16* bko = bglob + (size_t)kk*262144;
    #pragma unroll
    for (int jf = 0; jf < 8; ++jf)
      #pragma unroll
      for (int nf = 0; nf < 2; ++nf)
        acc[jf][nf] = (f32x4){0.f,0.f,0.f,0.f};

    // prologue: stage kt0 fully (6 loads) into buf 0
    #pragma unroll
    for (int u = 0; u < 4; ++u)
      gload_lds16(aglob + soff + (size_t)u*32768, LDS + (u*512 + tid)*8);
    #pragma unroll
    for (int u = 0; u < 2; ++u)
      gload_lds16(bko + soff + (size_t)u*32768, LDS + 32768 + (u*512 + tid)*8);

    for (int kt = 0; kt < 8; ++kt){
      int buf = kt & 1, nbuf = buf ^ 1;
      bf16* Ab = LDS + buf*16384;
      bf16* Bb = LDS + 32768 + buf*8192;
      bf16* An = LDS + nbuf*16384;
      bf16* Bn = LDS + 32768 + nbuf*8192;
      int mnext = (kt+1)*64;
      #pragma unroll
      for (int ph = 0; ph < 2; ++ph){
        // stage 3 loads for kt+1
        if (kt < 7){
          if (ph == 0){
            gload_lds16(aglob + soff + 0*32768 + mnext, An + (0*512 + tid)*8);
            gload_lds16(aglob + soff + 1*32768 + mnext, An + (1*512 + tid)*8);
            gload_lds16(aglob + soff + 2*32768 + mnext, An + (2*512 + tid)*8);
          } else {
            gload_lds16(aglob + soff + 3*32768 + mnext, An + (3*512 + tid)*8);
            gload_lds16(bko + soff + 0*32768 + mnext, Bn + (0*512 + tid)*8);
            gload_lds16(bko + soff + 1*32768 + mnext, Bn + (1*512 + tid)*8);
          }
        }
        if (ph == 0){
          if (kt < 7) asm volatile("s_waitcnt vmcnt(3)" ::: "memory");
          else        asm volatile("s_waitcnt vmcnt(0)" ::: "memory");
        }
        __builtin_amdgcn_sched_barrier(0);
        __builtin_amdgcn_s_barrier();
        __builtin_amdgcn_sched_barrier(0);

        bf16x8 a[8], bfr[2];
        #pragma unroll
        for (int jf = 0; jf < 8; ++jf)
          a[jf] = *reinterpret_cast<const bf16x8*>(&Ab[aoff[jf] + colx[ph]]);
        #pragma unroll
        for (int nf = 0; nf < 2; ++nf)
          bfr[nf] = *reinterpret_cast<const bf16x8*>(&Bb[boff[nf] + colx[ph]]);

        __builtin_amdgcn_s_setprio(1);
        #pragma unroll
        for (int jf = 0; jf < 8; ++jf)
          #pragma unroll
          for (int nf = 0; nf < 2; ++nf)
            acc[jf][nf] = MFMA16(a[jf], bfr[nf], acc[jf][nf]);
        __builtin_amdgcn_s_setprio(0);

        asm volatile("s_waitcnt lgkmcnt(0)" ::: "memory");
        __builtin_amdgcn_sched_barrier(0);
        __builtin_amdgcn_s_barrier();
      }
    }

    // ---- kk boundary: dump V-tile into VT[n:128][j:256] (16B-granule XOR) --
    // VT = LDS bytes [0,65536) aliasing the A bufs (all A reads sealed above)
    char* VTb = (char*)LDS;
    #pragma unroll
    for (int jf = 0; jf < 8; ++jf){
      int jb = wm*128 + jf*16 + lg*4;
      int jc16 = jb >> 3, jlow = (jb >> 2) & 1;
      #pragma unroll
      for (int nf = 0; nf < 2; ++nf){
        int n = wn2*32 + nf*16 + l15;
        bf16x4 pk;
        #pragma unroll
        for (int r = 0; r < 4; ++r) pk[r] = (bf16)acc[jf][nf][r];
        *reinterpret_cast<bf16x4*>(
            VTb + n*512 + ((jc16 ^ (n & 31)) << 4) + (jlow << 3)) = pk;
      }
    }
    asm volatile("s_waitcnt lgkmcnt(0)" ::: "memory");
    __builtin_amdgcn_sched_barrier(0);
    __builtin_amdgcn_s_barrier();

    // ---- cheb contraction: wave w -> tloc = w>>1, n-half = (w&1)*64 --------
    {
      int tloc = w >> 1, nbase = (w & 1)*64;
      #pragma unroll
      for (int ks2 = 0; ks2 < 2; ++ks2){
        bf16x8 bc[4];
        #pragma unroll
        for (int cf = 0; cf < 4; ++cf)
          bc[cf] = *reinterpret_cast<const bf16x8*>(
              cp + (((kk*2 + ks2)*4 + cf)*64 + l)*8);
        #pragma unroll
        for (int rf2 = 0; rf2 < 4; ++rf2){
          int nloc = nbase + rf2*16 + l15;
          int jc16 = tloc*8 + ks2*4 + lg;
          bf16x8 a2 = *reinterpret_cast<const bf16x8*>(
              VTb + nloc*512 + ((jc16 ^ (nloc & 31)) << 4));
          #pragma unroll
          for (int cf = 0; cf < 4; ++cf)
            acc2[rf2][cf] = MFMA16(a2, bc[cf], acc2[rf2][cf]);
        }
      }
    }
    asm volatile("s_waitcnt lgkmcnt(0)" ::: "memory");
    __builtin_amdgcn_sched_barrier(0);
    __builtin_amdgcn_s_barrier();      // VT reads sealed before next kk stages
  }

  // ---- epilogue: SP[row=(tloc*128+nloc)][o] = acc2 + cheb_b ---------------
  bf16* SP = LDS;                       // 512 rows x 64 o = 64KB
  float cbv[4];
  #pragma unroll
  for (int cf = 0; cf < 4; ++cf) cbv[cf] = cb[cf*16 + l15];
  #pragma unroll
  for (int rf2 = 0; rf2 < 4; ++rf2){
    int rowb = w*64 + rf2*16 + lg*4;
    #pragma unroll
    for (int cf = 0; cf < 4; ++cf){
      int o = cf*16 + l15;
      #pragma unroll
      for (int r = 0; r < 4; ++r)
        SP[(rowb + r)*64 + o] = (bf16)(acc2[rf2][cf][r] + cbv[cf]);
    }
  }
  __syncthreads();
  int b = jt >> 4, t0 = (jt & 15)*4;
  #pragma unroll
  for (int q = 0; q < 8; ++q){
    int flat = q*512 + tid;             // 4096 chunks of 8 elems
    int row = flat >> 3, oc = (flat & 7)*8;
    int tloc2 = row >> 7, n = N0 + (row & 127);
    bf16x8 vv = *reinterpret_cast<const bf16x8*>(&SP[row*64 + oc]);
    *reinterpret_cast<bf16x8*>(
        &spm[(((size_t)b*512 + n)*64 + (t0 + tloc2))*64 + oc]) = vv;
  }
}

// ---------------- fusion: gate/res MFMA + combine; writes bf16 out_pre -----
__global__ __launch_bounds__(256,4) void k_fusion(const bf16* __restrict__ spm,
    const bf16* __restrict__ t2, const bf16* __restrict__ xlb,
    const bf16* __restrict__ gp, const bf16* __restrict__ rp,
    const float* __restrict__ sc2, const float* __restrict__ sh2,
    const float* __restrict__ gateb, bf16* __restrict__ pre,
    float* __restrict__ part){
  int tid = threadIdx.x, w = tid >> 6, l = tid & 63, l15 = l & 15, lg = l >> 4;
  int blk = blockIdx.x;
  int b = blk >> 9, n = blk & 511;
  size_t rowbase = (size_t)blk * 64;
  int t = w*16 + l15;
  f32x4 ag[4] = {}, ar[4] = {};
  #pragma unroll
  for (int ks = 0; ks < 4; ++ks){                 // gate: K=128 = [spatial|t2bn]
    bf16x8 a;
    if (ks < 2){
      a = *reinterpret_cast<const bf16x8*>(spm + (rowbase + t)*64 + ks*32 + lg*8);
    } else {
      int i0 = (ks-2)*32 + lg*8;
      bf16x8 raw = *reinterpret_cast<const bf16x8*>(t2 + (rowbase + t)*64 + i0);
      #pragma unroll
      for (int e = 0; e < 8; ++e){
        float f = (float)raw[e]*sc2[i0+e] + sh2[i0+e];
        a[e] = (bf16)fmaxf(f, 0.f);
      }
    }
    #pragma unroll
    for (int cf = 0; cf < 4; ++cf){
      bf16x8 bfr = *reinterpret_cast<const bf16x8*>(gp + ((ks*4 + cf)*64 + l)*8);
      ag[cf] = MFMA16(a, bfr, ag[cf]);
    }
  }
  #pragma unroll
  for (int ks = 0; ks < 2; ++ks){                 // res: K=64 on x
    bf16x8 a = *reinterpret_cast<const bf16x8*>(xlb + (rowbase + t)*64 + ks*32 + lg*8);
    #pragma unroll
    for (int cf = 0; cf < 4; ++cf){
      bf16x8 bfr = *reinterpret_cast<const bf16x8*>(rp + ((ks*4 + cf)*64 + l)*8);
      ar[cf] = MFMA16(a, bfr, ar[cf]);
    }
  }
  __shared__ float ssum[4][4][16], ssq[4][4][16];
  int tb = w*16 + lg*4;
  #pragma unroll
  for (int cf = 0; cf < 4; ++cf){
    int o = cf*16 + l15;
    float gb = gateb[o], sco = sc2[o], sho = sh2[o];
    float s = 0.f, q = 0.f;
    bf16x4 ov;
    #pragma unroll
    for (int r = 0; r < 4; ++r){
      size_t row = rowbase + tb + r;
      float z = ag[cf][r] + gb;
      float g = 1.f/(1.f + __expf(-z));
      float spv = (float)spm[row*64 + o];
      float tv  = (float)t2[row*64 + o];
      tv = fmaxf(tv*sco + sho, 0.f);
      float val = g*spv + (1.f - g)*tv + ar[cf][r];
      ov[r] = (bf16)val;
      s += val; q += val*val;
    }
    *reinterpret_cast<bf16x4*>(pre + (((size_t)b*64 + o)*512 + n)*64 + tb) = ov;
    s += __shfl_xor(s, 16); s += __shfl_xor(s, 32);
    q += __shfl_xor(q, 16); q += __shfl_xor(q, 32);
    if (lg == 0){ ssum[w][cf][l15] = s; ssq[w][cf][l15] = q; }
  }
  __syncthreads();
  if (tid < 64){
    int cf = tid >> 4, c = tid & 15;
    float s = ssum[0][cf][c]+ssum[1][cf][c]+ssum[2][cf][c]+ssum[3][cf][c];
    float q = ssq[0][cf][c]+ssq[1][cf][c]+ssq[2][cf][c]+ssq[3][cf][c];
    part[(size_t)blk*128 + tid*2]     = s;
    part[(size_t)blk*128 + tid*2 + 1] = q;
  }
}

// ---------------- BN3: read bf16 out_pre, write fp32 d_out ------------------
__global__ __launch_bounds__(256) void k_bn3(const bf16* __restrict__ pre,
    float* __restrict__ out,
    const float* __restrict__ sc, const float* __restrict__ sh){
  size_t total8 = (size_t)BB*CC*NN*TT/8;
  for (size_t i8 = (size_t)blockIdx.x*256 + threadIdx.x; i8 < total8;
       i8 += (size_t)gridDim.x*256){
    bf16x8 v = reinterpret_cast<const bf16x8*>(pre)[i8];
    int o = (int)(i8 >> 12) & 63;                  // n*t = 32768 per (b,o)
    float a = sc[o], bsh = sh[o];
    float4 r0, r1;
    r0.x = (float)v[0]*a + bsh; r0.y = (float)v[1]*a + bsh;
    r0.z = (float)v[2]*a + bsh; r0.w = (float)v[3]*a + bsh;
    r1.x = (float)v[4]*a + bsh; r1.y = (float)v[5]*a + bsh;
    r1.z = (float)v[6]*a + bsh; r1.w = (float)v[7]*a + bsh;
    reinterpret_cast<float4*>(out)[i8*2]     = r0;
    reinterpret_cast<float4*>(out)[i8*2 + 1] = r1;
  }
}

extern "C" void kernel_launch(void* const* d_in, const int* in_sizes, int n_in,
                              void* d_out, int out_size, void* d_ws, size_t ws_size,
                              hipStream_t stream){
  (void)in_sizes; (void)n_in; (void)out_size; (void)ws_size;
  const float* x   = (const float*)d_in[0];
  const float* adj = (const float*)d_in[1];
  const float* cw  = (const float*)d_in[2];
  const float* cb  = (const float*)d_in[3];
  const float* w1  = (const float*)d_in[4];
  // d_in[5] = b1 (cancels in BN1)
  const float* g1  = (const float*)d_in[6];
  const float* be1 = (const float*)d_in[7];
  const float* w2  = (const float*)d_in[8];
  // d_in[9] = b2 (cancels in BN2)
  const float* g2  = (const float*)d_in[10];
  const float* be2 = (const float*)d_in[11];
  const float* gw  = (const float*)d_in[12];
  const float* gb  = (const float*)d_in[13];
  const float* rw  = (const float*)d_in[14];
  // d_in[15] = res_b (cancels in BN3)
  const float* g3  = (const float*)d_in[16];
  const float* be3 = (const float*)d_in[17];
  float* out = (float*)d_out;

  char* ws = (char*)d_ws;
  size_t off = 0;
  auto alloc = [&](size_t bytes)->char*{
    char* p = ws + off; off += (bytes + 255) & ~(size_t)255; return p;
  };
  bf16* xlb  = (bf16*)alloc((size_t)PP*64*2);        // 67MB channel-last x
  bf16* xmt  = (bf16*)alloc((size_t)PP*64*2);        // 67MB; reused as out_pre
  bf16* t1   = (bf16*)alloc((size_t)PP*64*2);        // 67MB; reused as spm
  bf16* t2   = (bf16*)alloc((size_t)PP*64*2);        // 67MB
  bf16* spm  = t1;                                   // alias (t1 dead after conv2)
  bf16* pre  = xmt;                                  // alias (xmt dead after gemm1)
  bf16* adjb = (bf16*)alloc((size_t)KCH*512*512*2);
  bf16* w1p  = (bf16*)alloc(6*2048*2);
  bf16* w2p  = (bf16*)alloc(6*2048*2);
  bf16* cp   = (bf16*)alloc(6*2048*2);
  bf16* gp   = (bf16*)alloc(4*2048*2);
  bf16* rp   = (bf16*)alloc(2*2048*2);
  float* part = (float*)alloc((size_t)8192*128*4);   // shared partials (sequential)
  float* s1sc = (float*)alloc(256); float* s1sh = (float*)alloc(256);
  float* s2sc = (float*)alloc(256); float* s2sh = (float*)alloc(256);
  float* s3sc = (float*)alloc(256); float* s3sh = (float*)alloc(256);

  k_prep <<<dim3(3168), dim3(256), 0, stream>>>(adj, w1, w2, cw, gw, rw,
                                                adjb, w1p, w2p, cp, gp, rp);
  k_xprep<<<dim3(1024), dim3(256), 0, stream>>>(x, xlb, xmt);

  k_conv <<<dim3(8192), dim3(256), 0, stream>>>(xlb, w1p, t1, part, nullptr, nullptr);
  k_stats<<<dim3(64),   dim3(256), 0, stream>>>(part, 8192, g1, be1, s1sc, s1sh);
  k_conv <<<dim3(8192), dim3(256), 0, stream>>>(t1, w2p, t2, part, s1sc, s1sh);
  k_stats<<<dim3(64),   dim3(256), 0, stream>>>(part, 8192, g2, be2, s2sc, s2sh);

  k_gemm1<<<dim3(1024), dim3(512), 0, stream>>>(xmt, adjb, cp, cb, spm);

  k_fusion<<<dim3(8192), dim3(256), 0, stream>>>(spm, t2, xlb, gp, rp,
                                                 s2sc, s2sh, gb, pre, part);
  k_stats<<<dim3(64),   dim3(256), 0, stream>>>(part, 8192, g3, be3, s3sc, s3sh);
  k_bn3  <<<dim3(2048), dim3(256), 0, stream>>>(pre, out, s3sc, s3sh);
}

// Round 14
// 546.895 us; speedup vs baseline: 1.4722x; 1.0133x over previous
//
#include <hip/hip_runtime.h>
#include <hip/hip_bf16.h>
#include <cstdint>

// Problem dims
#define BB 16
#define CC 64
#define NN 512
#define TT 64
#define KCH 3
#define PP (BB*NN*TT)      // 524288 points
#define EPSB 1e-5f

typedef __bf16 bf16;
typedef __bf16 bf16x8 __attribute__((ext_vector_type(8)));
typedef __bf16 bf16x4 __attribute__((ext_vector_type(4)));
typedef float  f32x4  __attribute__((ext_vector_type(4)));

#define MFMA16(A,Bv,Cv) __builtin_amdgcn_mfma_f32_16x16x32_bf16((A),(Bv),(Cv),0,0,0)

__device__ __forceinline__ void gload_lds16(const bf16* g, bf16* l){
  __builtin_amdgcn_global_load_lds(
      (const __attribute__((address_space(1))) void*)g,
      (__attribute__((address_space(3))) void*)l, 16, 0, 0);
}

// ---------------- prep (merged): adjb transpose + weight fragment prep -----
__global__ __launch_bounds__(256) void k_prep(const float* __restrict__ adj,
    const float* __restrict__ w1, const float* __restrict__ w2,
    const float* __restrict__ cw, const float* __restrict__ gw,
    const float* __restrict__ rw, bf16* __restrict__ adjb,
    bf16* __restrict__ w1p, bf16* __restrict__ w2p, bf16* __restrict__ cp,
    bf16* __restrict__ gp, bf16* __restrict__ rp){
  int blk = blockIdx.x, tid = threadIdx.x;
  if (blk < 3072){
    int idx = blk*256 + tid;
    int m = idx & 511, n = (idx >> 9) & 511, k = idx >> 18;
    adjb[idx] = (bf16)adj[((size_t)(k*512 + m))*512 + n];
    return;
  }
  int e0 = (blk - 3072)*256 + tid;                  // [0, 24576)
  if (e0 < 12288){                                  // K=192 groups (conv & cheb)
    int e = e0;
    int j = e&7, lane = (e>>3)&63, cf = (e>>9)&3, ks = e>>11;
    int k = ks*32 + (lane>>4)*8 + j, col = cf*16 + (lane&15);
    int kk = k >> 6, i = k & 63;
    w1p[e] = (bf16)w1[(col*64 + i)*3 + kk];
    w2p[e] = (bf16)w2[(col*64 + i)*3 + kk];
    cp[e]  = (bf16)cw[((size_t)kk*64 + i)*64 + col];
  } else if (e0 < 20480){                           // K=128 (gate)
    int e = e0 - 12288;
    int j = e&7, lane = (e>>3)&63, cf = (e>>9)&3, ks = e>>11;
    int k = ks*32 + (lane>>4)*8 + j, col = cf*16 + (lane&15);
    gp[e] = (bf16)gw[col*128 + k];
  } else {                                          // K=64 (res)
    int e = e0 - 20480;
    int j = e&7, lane = (e>>3)&63, cf = (e>>9)&3, ks = e>>11;
    int k = ks*32 + (lane>>4)*8 + j, col = cf*16 + (lane&15);
    rp[e] = (bf16)rw[col*64 + k];
  }
}

// ---------------- fused x prep: one read of x -> xlb AND xmt ----------------
__global__ __launch_bounds__(256) void k_xprep(const float* __restrict__ x,
    bf16* __restrict__ xlb, bf16* __restrict__ xmt){
  __shared__ bf16 T[32768];               // 64KB
  int bid = blockIdx.x;
  int b = bid >> 6, i0 = ((bid >> 3) & 7)*8, n0 = (bid & 7)*64;
  int tid = threadIdx.x;
  #pragma unroll 4
  for (int it = 0; it < 32; ++it){
    int flat = it*256 + tid;              // [0,8192)
    int t4 = flat & 15, n = (flat >> 4) & 63, i = flat >> 10;
    float4 v = *reinterpret_cast<const float4*>(
        x + ((size_t)((b*64 + i0 + i)*512) + (n0 + n))*64 + t4*4);
    int s = t4 ^ ((n + 2*i) & 15);
    bf16x4 pk; pk[0]=(bf16)v.x; pk[1]=(bf16)v.y; pk[2]=(bf16)v.z; pk[3]=(bf16)v.w;
    *reinterpret_cast<bf16x4*>(&T[(i*64 + n)*64 + s*4]) = pk;
  }
  __syncthreads();
  // xmt emission
  #pragma unroll 4
  for (int it = 0; it < 16; ++it){
    int flat = it*256 + tid;              // [0,4096)
    int mc = flat & 7, i = (flat >> 3) & 7, t = flat >> 6;
    bf16x8 o;
    #pragma unroll
    for (int e = 0; e < 8; ++e){
      int m = mc*8 + e;
      int s = (t >> 2) ^ ((m + 2*i) & 15);
      o[e] = T[(i*64 + m)*64 + s*4 + (t & 3)];
    }
    *reinterpret_cast<bf16x8*>(
        &xmt[((size_t)((b*64 + t)*64) + i0 + i)*512 + n0 + mc*8]) = o;
  }
  // xlb emission
  #pragma unroll 4
  for (int it = 0; it < 16; ++it){
    int flat = it*256 + tid;              // [0,4096)
    int t = flat & 63, n = flat >> 6;
    bf16x8 o;
    #pragma unroll
    for (int e = 0; e < 8; ++e){
      int s = (t >> 2) ^ ((n + 2*e) & 15);
      o[e] = T[(e*64 + n)*64 + s*4 + (t & 3)];
    }
    *reinterpret_cast<bf16x8*>(
        &xlb[(((size_t)b*512 + n0 + n)*64 + t)*64 + i0]) = o;
  }
}

// ---------------- temporal conv (1x3) as tall GEMM; optional BN+relu on load
__global__ __launch_bounds__(256,4) void k_conv(const bf16* __restrict__ in,
    const bf16* __restrict__ wp, bf16* __restrict__ outp, float* __restrict__ part,
    const float* __restrict__ sc, const float* __restrict__ sh){
  int tid = threadIdx.x, w = tid >> 6, l = tid & 63, l15 = l & 15, lg = l >> 4;
  int blk = blockIdx.x;
  size_t rowbase = (size_t)blk * 64;
  const bf16* xr = in + rowbase * 64;
  int t = w*16 + l15;
  f32x4 acc[4] = {};
  #pragma unroll
  for (int ks = 0; ks < 6; ++ks){
    int dt = ks >> 1, kh = ks & 1;
    int ts = t + dt - 1;
    bf16x8 a = {};
    if (ts >= 0 && ts < 64){
      a = *reinterpret_cast<const bf16x8*>(xr + ts*64 + kh*32 + lg*8);
      if (sc){                                  // BN1+relu applied on load
        int i0 = kh*32 + lg*8;
        #pragma unroll
        for (int e = 0; e < 8; ++e){
          float f = (float)a[e]*sc[i0+e] + sh[i0+e];
          a[e] = (bf16)fmaxf(f, 0.f);
        }
      }
    }
    #pragma unroll
    for (int cf = 0; cf < 4; ++cf){
      bf16x8 bfr = *reinterpret_cast<const bf16x8*>(wp + ((ks*4 + cf)*64 + l)*8);
      acc[cf] = MFMA16(a, bfr, acc[cf]);
    }
  }
  __shared__ float ssum[4][4][16], ssq[4][4][16];
  #pragma unroll
  for (int cf = 0; cf < 4; ++cf){
    int o = cf*16 + l15;
    float s = 0.f, q = 0.f;
    #pragma unroll
    for (int r = 0; r < 4; ++r){
      float vv = acc[cf][r];
      int to = w*16 + lg*4 + r;
      outp[(rowbase + to)*64 + o] = (bf16)vv;
      s += vv; q += vv*vv;
    }
    s += __shfl_xor(s, 16); s += __shfl_xor(s, 32);
    q += __shfl_xor(q, 16); q += __shfl_xor(q, 32);
    if (lg == 0){ ssum[w][cf][l15] = s; ssq[w][cf][l15] = q; }
  }
  __syncthreads();
  if (tid < 64){
    int cf = tid >> 4, c = tid & 15;
    float s = ssum[0][cf][c]+ssum[1][cf][c]+ssum[2][cf][c]+ssum[3][cf][c];
    float q = ssq[0][cf][c]+ssq[1][cf][c]+ssq[2][cf][c]+ssq[3][cf][c];
    part[(size_t)blk*128 + tid*2]     = s;
    part[(size_t)blk*128 + tid*2 + 1] = q;
  }
}

// ---------------- BN stats finalize: partials -> scale/shift ----------------
__global__ __launch_bounds__(256) void k_stats(const float* __restrict__ part, int nb,
    const float* __restrict__ g, const float* __restrict__ be,
    float* __restrict__ sc, float* __restrict__ sh){
  int c = blockIdx.x, tid = threadIdx.x;
  float s = 0.f, q = 0.f;
  for (int i = tid; i < nb; i += 256){
    s += part[(size_t)i*128 + c*2];
    q += part[(size_t)i*128 + c*2 + 1];
  }
  __shared__ float rs[256], rq[256];
  rs[tid] = s; rq[tid] = q; __syncthreads();
  for (int st = 128; st > 0; st >>= 1){
    if (tid < st){ rs[tid] += rs[tid+st]; rq[tid] += rq[tid+st]; }
    __syncthreads();
  }
  if (tid == 0){
    float cnt = (float)PP;
    float mean = rs[0]/cnt, var = rq[0]/cnt - mean*mean;
    float r = rsqrtf(var + EPSB);
    sc[c] = g[c]*r;
    sh[c] = be[c] - mean*g[c]*r;
  }
}

// ---------------- fused GEMM1+cheb: spm[(b,n,t)][o] ------------------------
// v13: register diet. BM=128(j) x BN=128(n), BK=64, 8 waves (2Mx4N), 2 dbuf,
// 64KB LDS (A bufs @0/8192 elems, B bufs @16384/24576) -> 2 blocks/CU.
// acc[4][2]+acc2[2][4]+frags ~= 115 VGPR -> fits 128 cap, NO spills.
// Per K-tile: 2 phases {ph0: stage 2xA, vmcnt(2) | ph1: stage 2xB}, each
// phase {barrier, 6 ds_read, 8 MFMA + setprio, lgkm(0), barrier}. T2 2-way
// swizzle. VT[128n][128j] (32KB, aliases A bufs) at kk boundaries.
__global__ __launch_bounds__(512,2) void k_gemm1(const bf16* __restrict__ xmt,
    const bf16* __restrict__ adjb, const bf16* __restrict__ cp,
    const float* __restrict__ cb, bf16* __restrict__ spm){
  __shared__ __align__(16) bf16 LDS[32768];        // 64KB

  int tid = threadIdx.x, w = tid >> 6, l = tid & 63, l15 = l & 15, lg = l >> 4;
  int wm = w >> 2, wn2 = w & 3;        // j-half (64 rows), n-quarter (32 cols)

  // bijective XCD swizzle over 2048 blocks; nt innermost
  int orig = blockIdx.x;
  int wg = (orig & 7) * 256 + (orig >> 3);
  int jt = wg >> 2, nt = wg & 3;
  int J0 = jt*128, N0 = nt*128;

  const bf16* aglob = xmt + (size_t)J0*512;
  const bf16* bglob = adjb + (size_t)N0*512;

  // staging map: u in {0,1}: row = u*64 + (tid>>3), chunk cg = (tid&7)^(row&7)
  int srow = tid >> 3, scn = (tid & 7) ^ ((tid >> 3) & 7);
  size_t soff = (size_t)srow*512 + scn*8;
  // LDS dest: buf*8192 + u*4096 + tid*8  (== wave-uniform + lane*16B)

  // ds_read offsets (elements): colx shared by A and B (row&7 == l15&7)
  int colx[2];
  #pragma unroll
  for (int ph = 0; ph < 2; ++ph) colx[ph] = ((ph*4 + lg) ^ (l15 & 7))*8;
  int aoff[4], boff[2];
  #pragma unroll
  for (int jf = 0; jf < 4; ++jf) aoff[jf] = (wm*64 + jf*16 + l15)*64;
  #pragma unroll
  for (int nf = 0; nf < 2; ++nf) boff[nf] = (wn2*32 + nf*16 + l15)*64;

  f32x4 acc[4][2];
  f32x4 acc2[2][4] = {};

  for (int kk = 0; kk < 3; ++kk){
    const bf16* bko = bglob + (size_t)kk*262144;
    #pragma unroll
    for (int jf = 0; jf < 4; ++jf)
      #pragma unroll
      for (int nf = 0; nf < 2; ++nf)
        acc[jf][nf] = (f32x4){0.f,0.f,0.f,0.f};

    // prologue: stage kt0 fully (4 loads) into buf 0
    gload_lds16(aglob + soff,          LDS + tid*8);
    gload_lds16(aglob + soff + 32768,  LDS + 4096 + tid*8);
    gload_lds16(bko   + soff,          LDS + 16384 + tid*8);
    gload_lds16(bko   + soff + 32768,  LDS + 16384 + 4096 + tid*8);

    for (int kt = 0; kt < 8; ++kt){
      int buf = kt & 1, nbuf = buf ^ 1;
      bf16* Ab = LDS + buf*8192;
      bf16* Bb = LDS + 16384 + buf*8192;
      int mnext = (kt+1)*64;
      #pragma unroll
      for (int ph = 0; ph < 2; ++ph){
        if (kt < 7){
          if (ph == 0){
            gload_lds16(aglob + soff + mnext,         LDS + nbuf*8192 + tid*8);
            gload_lds16(aglob + soff + 32768 + mnext, LDS + nbuf*8192 + 4096 + tid*8);
          } else {
            gload_lds16(bko + soff + mnext,           LDS + 16384 + nbuf*8192 + tid*8);
            gload_lds16(bko + soff + 32768 + mnext,   LDS + 16384 + nbuf*8192 + 4096 + tid*8);
          }
        }
        if (ph == 0){
          if (kt < 7) asm volatile("s_waitcnt vmcnt(2)" ::: "memory");
          else        asm volatile("s_waitcnt vmcnt(0)" ::: "memory");
        }
        __builtin_amdgcn_sched_barrier(0);
        __builtin_amdgcn_s_barrier();
        __builtin_amdgcn_sched_barrier(0);

        bf16x8 a[4], bfr[2];
        #pragma unroll
        for (int jf = 0; jf < 4; ++jf)
          a[jf] = *reinterpret_cast<const bf16x8*>(&Ab[aoff[jf] + colx[ph]]);
        #pragma unroll
        for (int nf = 0; nf < 2; ++nf)
          bfr[nf] = *reinterpret_cast<const bf16x8*>(&Bb[boff[nf] + colx[ph]]);

        __builtin_amdgcn_s_setprio(1);
        #pragma unroll
        for (int jf = 0; jf < 4; ++jf)
          #pragma unroll
          for (int nf = 0; nf < 2; ++nf)
            acc[jf][nf] = MFMA16(a[jf], bfr[nf], acc[jf][nf]);
        __builtin_amdgcn_s_setprio(0);

        asm volatile("s_waitcnt lgkmcnt(0)" ::: "memory");
        __builtin_amdgcn_sched_barrier(0);
        __builtin_amdgcn_s_barrier();
      }
    }

    // ---- kk boundary: dump V-tile into VT[n:128][j:128] (16B-granule XOR) --
    // VT = LDS bytes [0,32768) aliasing the A bufs (A reads + DMA sealed)
    char* VTb = (char*)LDS;
    #pragma unroll
    for (int jf = 0; jf < 4; ++jf){
      int jb16 = wm*8 + jf*2 + (lg >> 1);         // (j0=wm*64+jf*16+lg*4)>>3
      int jlow = lg & 1;
      #pragma unroll
      for (int nf = 0; nf < 2; ++nf){
        int n = wn2*32 + nf*16 + l15;
        bf16x4 pk;
        #pragma unroll
        for (int r = 0; r < 4; ++r) pk[r] = (bf16)acc[jf][nf][r];
        *reinterpret_cast<bf16x4*>(
            VTb + n*256 + ((jb16 ^ (n & 15)) << 4) + (jlow << 3)) = pk;
      }
    }
    asm volatile("s_waitcnt lgkmcnt(0)" ::: "memory");
    __builtin_amdgcn_sched_barrier(0);
    __builtin_amdgcn_s_barrier();

    // ---- cheb: wave -> tloc = w>>2, nbase = (w&3)*32; 2 rf2 x 16 rows -----
    {
      int tloc = w >> 2, nbase = (w & 3)*32;
      #pragma unroll
      for (int ks2 = 0; ks2 < 2; ++ks2){
        bf16x8 bc[4];
        #pragma unroll
        for (int cf = 0; cf < 4; ++cf)
          bc[cf] = *reinterpret_cast<const bf16x8*>(
              cp + (((kk*2 + ks2)*4 + cf)*64 + l)*8);
        #pragma unroll
        for (int rf2 = 0; rf2 < 2; ++rf2){
          int nloc = nbase + rf2*16 + l15;
          int jb16 = tloc*8 + ks2*4 + lg;
          bf16x8 a2 = *reinterpret_cast<const bf16x8*>(
              VTb + nloc*256 + ((jb16 ^ (nloc & 15)) << 4));
          #pragma unroll
          for (int cf = 0; cf < 4; ++cf)
            acc2[rf2][cf] = MFMA16(a2, bc[cf], acc2[rf2][cf]);
        }
      }
    }
    asm volatile("s_waitcnt lgkmcnt(0)" ::: "memory");
    __builtin_amdgcn_sched_barrier(0);
    __builtin_amdgcn_s_barrier();      // VT reads sealed before next kk stages
  }

  // ---- epilogue: SP[row=(tloc*128+nloc)][o] = acc2 + cheb_b (32KB) --------
  __syncthreads();
  bf16* SP = LDS;                       // 256 rows x 64 o = 32KB
  float cbv[4];
  #pragma unroll
  for (int cf = 0; cf < 4; ++cf) cbv[cf] = cb[cf*16 + l15];
  {
    int tloc = w >> 2, nbase = (w & 3)*32;
    #pragma unroll
    for (int rf2 = 0; rf2 < 2; ++rf2){
      int rowb = tloc*128 + nbase + rf2*16 + lg*4;
      #pragma unroll
      for (int cf = 0; cf < 4; ++cf){
        int o = cf*16 + l15;
        #pragma unroll
        for (int r = 0; r < 4; ++r)
          SP[(rowb + r)*64 + o] = (bf16)(acc2[rf2][cf][r] + cbv[cf]);
      }
    }
  }
  __syncthreads();
  int b = jt >> 5, t0 = (jt & 31)*2;
  #pragma unroll
  for (int q = 0; q < 4; ++q){
    int flat = q*512 + tid;             // 2048 chunks of 8 elems
    int row = flat >> 3, oc = (flat & 7)*8;
    int tl = row >> 7, n = N0 + (row & 127);
    bf16x8 vv = *reinterpret_cast<const bf16x8*>(&SP[row*64 + oc]);
    *reinterpret_cast<bf16x8*>(
        &spm[(((size_t)b*512 + n)*64 + (t0 + tl))*64 + oc]) = vv;
  }
}

// ---------------- fusion: gate/res MFMA + combine; writes bf16 out_pre -----
__global__ __launch_bounds__(256,4) void k_fusion(const bf16* __restrict__ spm,
    const bf16* __restrict__ t2, const bf16* __restrict__ xlb,
    const bf16* __restrict__ gp, const bf16* __restrict__ rp,
    const float* __restrict__ sc2, const float* __restrict__ sh2,
    const float* __restrict__ gateb, bf16* __restrict__ pre,
    float* __restrict__ part){
  int tid = threadIdx.x, w = tid >> 6, l = tid & 63, l15 = l & 15, lg = l >> 4;
  int blk = blockIdx.x;
  int b = blk >> 9, n = blk & 511;
  size_t rowbase = (size_t)blk * 64;
  int t = w*16 + l15;
  f32x4 ag[4] = {}, ar[4] = {};
  #pragma unroll
  for (int ks = 0; ks < 4; ++ks){                 // gate: K=128 = [spatial|t2bn]
    bf16x8 a;
    if (ks < 2){
      a = *reinterpret_cast<const bf16x8*>(spm + (rowbase + t)*64 + ks*32 + lg*8);
    } else {
      int i0 = (ks-2)*32 + lg*8;
      bf16x8 raw = *reinterpret_cast<const bf16x8*>(t2 + (rowbase + t)*64 + i0);
      #pragma unroll
      for (int e = 0; e < 8; ++e){
        float f = (float)raw[e]*sc2[i0+e] + sh2[i0+e];
        a[e] = (bf16)fmaxf(f, 0.f);
      }
    }
    #pragma unroll
    for (int cf = 0; cf < 4; ++cf){
      bf16x8 bfr = *reinterpret_cast<const bf16x8*>(gp + ((ks*4 + cf)*64 + l)*8);
      ag[cf] = MFMA16(a, bfr, ag[cf]);
    }
  }
  #pragma unroll
  for (int ks = 0; ks < 2; ++ks){                 // res: K=64 on x
    bf16x8 a = *reinterpret_cast<const bf16x8*>(xlb + (rowbase + t)*64 + ks*32 + lg*8);
    #pragma unroll
    for (int cf = 0; cf < 4; ++cf){
      bf16x8 bfr = *reinterpret_cast<const bf16x8*>(rp + ((ks*4 + cf)*64 + l)*8);
      ar[cf] = MFMA16(a, bfr, ar[cf]);
    }
  }
  __shared__ float ssum[4][4][16], ssq[4][4][16];
  int tb = w*16 + lg*4;
  #pragma unroll
  for (int cf = 0; cf < 4; ++cf){
    int o = cf*16 + l15;
    float gb = gateb[o], sco = sc2[o], sho = sh2[o];
    float s = 0.f, q = 0.f;
    bf16x4 ov;
    #pragma unroll
    for (int r = 0; r < 4; ++r){
      size_t row = rowbase + tb + r;
      float z = ag[cf][r] + gb;
      float g = 1.f/(1.f + __expf(-z));
      float spv = (float)spm[row*64 + o];
      float tv  = (float)t2[row*64 + o];
      tv = fmaxf(tv*sco + sho, 0.f);
      float val = g*spv + (1.f - g)*tv + ar[cf][r];
      ov[r] = (bf16)val;
      s += val; q += val*val;
    }
    *reinterpret_cast<bf16x4*>(pre + (((size_t)b*64 + o)*512 + n)*64 + tb) = ov;
    s += __shfl_xor(s, 16); s += __shfl_xor(s, 32);
    q += __shfl_xor(q, 16); q += __shfl_xor(q, 32);
    if (lg == 0){ ssum[w][cf][l15] = s; ssq[w][cf][l15] = q; }
  }
  __syncthreads();
  if (tid < 64){
    int cf = tid >> 4, c = tid & 15;
    float s = ssum[0][cf][c]+ssum[1][cf][c]+ssum[2][cf][c]+ssum[3][cf][c];
    float q = ssq[0][cf][c]+ssq[1][cf][c]+ssq[2][cf][c]+ssq[3][cf][c];
    part[(size_t)blk*128 + tid*2]     = s;
    part[(size_t)blk*128 + tid*2 + 1] = q;
  }
}

// ---------------- BN3: read bf16 out_pre, write fp32 d_out ------------------
__global__ __launch_bounds__(256) void k_bn3(const bf16* __restrict__ pre,
    float* __restrict__ out,
    const float* __restrict__ sc, const float* __restrict__ sh){
  size_t total8 = (size_t)BB*CC*NN*TT/8;
  for (size_t i8 = (size_t)blockIdx.x*256 + threadIdx.x; i8 < total8;
       i8 += (size_t)gridDim.x*256){
    bf16x8 v = reinterpret_cast<const bf16x8*>(pre)[i8];
    int o = (int)(i8 >> 12) & 63;                  // n*t = 32768 per (b,o)
    float a = sc[o], bsh = sh[o];
    float4 r0, r1;
    r0.x = (float)v[0]*a + bsh; r0.y = (float)v[1]*a + bsh;
    r0.z = (float)v[2]*a + bsh; r0.w = (float)v[3]*a + bsh;
    r1.x = (float)v[4]*a + bsh; r1.y = (float)v[5]*a + bsh;
    r1.z = (float)v[6]*a + bsh; r1.w = (float)v[7]*a + bsh;
    reinterpret_cast<float4*>(out)[i8*2]     = r0;
    reinterpret_cast<float4*>(out)[i8*2 + 1] = r1;
  }
}

extern "C" void kernel_launch(void* const* d_in, const int* in_sizes, int n_in,
                              void* d_out, int out_size, void* d_ws, size_t ws_size,
                              hipStream_t stream){
  (void)in_sizes; (void)n_in; (void)out_size; (void)ws_size;
  const float* x   = (const float*)d_in[0];
  const float* adj = (const float*)d_in[1];
  const float* cw  = (const float*)d_in[2];
  const float* cb  = (const float*)d_in[3];
  const float* w1  = (const float*)d_in[4];
  // d_in[5] = b1 (cancels in BN1)
  const float* g1  = (const float*)d_in[6];
  const float* be1 = (const float*)d_in[7];
  const float* w2  = (const float*)d_in[8];
  // d_in[9] = b2 (cancels in BN2)
  const float* g2  = (const float*)d_in[10];
  const float* be2 = (const float*)d_in[11];
  const float* gw  = (const float*)d_in[12];
  const float* gb  = (const float*)d_in[13];
  const float* rw  = (const float*)d_in[14];
  // d_in[15] = res_b (cancels in BN3)
  const float* g3  = (const float*)d_in[16];
  const float* be3 = (const float*)d_in[17];
  float* out = (float*)d_out;

  char* ws = (char*)d_ws;
  size_t off = 0;
  auto alloc = [&](size_t bytes)->char*{
    char* p = ws + off; off += (bytes + 255) & ~(size_t)255; return p;
  };
  bf16* xlb  = (bf16*)alloc((size_t)PP*64*2);        // 67MB channel-last x
  bf16* xmt  = (bf16*)alloc((size_t)PP*64*2);        // 67MB; reused as out_pre
  bf16* t1   = (bf16*)alloc((size_t)PP*64*2);        // 67MB; reused as spm
  bf16* t2   = (bf16*)alloc((size_t)PP*64*2);        // 67MB
  bf16* spm  = t1;                                   // alias (t1 dead after conv2)
  bf16* pre  = xmt;                                  // alias (xmt dead after gemm1)
  bf16* adjb = (bf16*)alloc((size_t)KCH*512*512*2);
  bf16* w1p  = (bf16*)alloc(6*2048*2);
  bf16* w2p  = (bf16*)alloc(6*2048*2);
  bf16* cp   = (bf16*)alloc(6*2048*2);
  bf16* gp   = (bf16*)alloc(4*2048*2);
  bf16* rp   = (bf16*)alloc(2*2048*2);
  float* part = (float*)alloc((size_t)8192*128*4);   // shared partials (sequential)
  float* s1sc = (float*)alloc(256); float* s1sh = (float*)alloc(256);
  float* s2sc = (float*)alloc(256); float* s2sh = (float*)alloc(256);
  float* s3sc = (float*)alloc(256); float* s3sh = (float*)alloc(256);

  k_prep <<<dim3(3168), dim3(256), 0, stream>>>(adj, w1, w2, cw, gw, rw,
                                                adjb, w1p, w2p, cp, gp, rp);
  k_xprep<<<dim3(1024), dim3(256), 0, stream>>>(x, xlb, xmt);

  k_conv <<<dim3(8192), dim3(256), 0, stream>>>(xlb, w1p, t1, part, nullptr, nullptr);
  k_stats<<<dim3(64),   dim3(256), 0, stream>>>(part, 8192, g1, be1, s1sc, s1sh);
  k_conv <<<dim3(8192), dim3(256), 0, stream>>>(t1, w2p, t2, part, s1sc, s1sh);
  k_stats<<<dim3(64),   dim3(256), 0, stream>>>(part, 8192, g2, be2, s2sc, s2sh);

  k_gemm1<<<dim3(2048), dim3(512), 0, stream>>>(xmt, adjb, cp, cb, spm);

  k_fusion<<<dim3(8192), dim3(256), 0, stream>>>(spm, t2, xlb, gp, rp,
                                                 s2sc, s2sh, gb, pre, part);
  k_stats<<<dim3(64),   dim3(256), 0, stream>>>(part, 8192, g3, be3, s3sc, s3sh);
  k_bn3  <<<dim3(2048), dim3(256), 0, stream>>>(pre, out, s3sc, s3sh);
}